// Round 16
// baseline (898.627 us; speedup 1.0000x reference)
//
#include <hip/hip_runtime.h>
#include <hip/hip_bf16.h>

#define DD 1024
#define HEADS 16
#define HDIM 64
#define NLAYER 4
#define FFDIM 4096
#define NVOCAB 32000
#define SEQ 1024

typedef __bf16 bf16_t;
typedef __bf16 bf16x8 __attribute__((ext_vector_type(8)));
typedef __bf16 bf16x4 __attribute__((ext_vector_type(4)));
typedef float f32x4 __attribute__((ext_vector_type(4)));

#define MFMA16(a, b, c) __builtin_amdgcn_mfma_f32_16x16x32_bf16((a), (b), (c), 0, 0, 0)

// async global->LDS, 16B per lane, dest = wave-uniform base + lane*16
#define GLD16(gp, lp) \
    __builtin_amdgcn_global_load_lds( \
        (const __attribute__((address_space(1))) void*)(gp), \
        (__attribute__((address_space(3))) void*)(lp), 16, 0, 0)

// raw barrier (no implicit vmcnt/lgkm drain) with compile-time motion fences
#define BAR() do { __builtin_amdgcn_sched_barrier(0); \
                   __builtin_amdgcn_s_barrier(); \
                   __builtin_amdgcn_sched_barrier(0); } while (0)
#define WAITVM(n) asm volatile("s_waitcnt vmcnt(" #n ")" ::: "memory")

static __device__ __forceinline__ bf16x8 pack8(float4 u, float4 v) {
    bf16x8 r;
    r[0] = (bf16_t)u.x; r[1] = (bf16_t)u.y; r[2] = (bf16_t)u.z; r[3] = (bf16_t)u.w;
    r[4] = (bf16_t)v.x; r[5] = (bf16_t)v.y; r[6] = (bf16_t)v.z; r[7] = (bf16_t)v.w;
    return r;
}

// ---------------------------------------------------------------------------
// Batched f32 -> bf16 convert, 16 elems/thread. Segment counts % 4096 == 0.
// ---------------------------------------------------------------------------
struct CvtBatch {
    const float* src[7];
    bf16_t*      dst[7];
    int          blk0[7];   // starting block of each segment
    int          nseg;
};

__global__ __launch_bounds__(256) void cvt_batch(CvtBatch cb) {
    const int b = blockIdx.x;
    int s = 0;
    #pragma unroll
    for (int t = 1; t < 7; ++t)
        if (t < cb.nseg && b >= cb.blk0[t]) s = t;
    const long i = ((long)(b - cb.blk0[s]) * 256 + threadIdx.x) * 16;
    float4 a0 = *(const float4*)(cb.src[s] + i);
    float4 a1 = *(const float4*)(cb.src[s] + i + 4);
    float4 a2 = *(const float4*)(cb.src[s] + i + 8);
    float4 a3 = *(const float4*)(cb.src[s] + i + 12);
    *(bf16x8*)(cb.dst[s] + i)     = pack8(a0, a1);
    *(bf16x8*)(cb.dst[s] + i + 8) = pack8(a2, a3);
}

// ---------------------------------------------------------------------------
// Head-rope cos/sin tables: [S][32]
// ---------------------------------------------------------------------------
__global__ __launch_bounds__(256) void ropetab_kernel(
    const float* __restrict__ inv_freq, const float* __restrict__ rbias,
    float* __restrict__ ctab, float* __restrict__ stab)
{
    int idx = blockIdx.x * 256 + threadIdx.x;     // s*32 + i
    int s = idx >> 5, i = idx & 31;
    float fr = (float)s * inv_freq[i] + rbias[idx];
    ctab[idx] = cosf(fr);
    stab[idx] = sinf(fr);
}

// ---------------------------------------------------------------------------
// Embedding + decoder-level rotary
// ---------------------------------------------------------------------------
__global__ __launch_bounds__(512) void embed_rope_kernel(
    const int* __restrict__ x, const float* __restrict__ tok_emb,
    const float* __restrict__ pos_emb, const float* __restrict__ inv_freq,
    const float* __restrict__ rbias, float* __restrict__ h, int S)
{
    const int row = blockIdx.x;      // b*S + s
    const int s = row % S;
    const int i = threadIdx.x;       // 0..511 pair index
    const int tok = x[row];
    const float* e = tok_emb + (size_t)tok * DD;
    const float* p = pos_emb + (size_t)s * DD;
    float a = e[2*i]   + p[2*i];
    float b = e[2*i+1] + p[2*i+1];
    float fr = (float)s * inv_freq[i] + rbias[(size_t)s * (DD/2) + i];
    float c = cosf(fr), sn = sinf(fr);
    h[(size_t)row*DD + 2*i]   = a*c - b*sn;
    h[(size_t)row*DD + 2*i+1] = a*sn + b*c;
}

// ---------------------------------------------------------------------------
// RMSNorm with bf16 output
// ---------------------------------------------------------------------------
__global__ __launch_bounds__(256) void rmsnorm_kernel(
    const float* __restrict__ x, const float* __restrict__ w,
    bf16_t* __restrict__ y)
{
    const int row = blockIdx.x;
    const float* xr = x + (size_t)row * DD;
    float ss = 0.f;
    for (int j = threadIdx.x; j < DD; j += 256) { float v = xr[j]; ss += v*v; }
    for (int off = 32; off > 0; off >>= 1) ss += __shfl_down(ss, off, 64);
    __shared__ float r[4];
    if ((threadIdx.x & 63) == 0) r[threadIdx.x >> 6] = ss;
    __syncthreads();
    float tot = r[0] + r[1] + r[2] + r[3];
    float sc = rsqrtf(tot * (1.0f/(float)DD) + 1e-8f);
    for (int j = threadIdx.x; j < DD; j += 256)
        y[(size_t)row*DD + j] = (bf16_t)(xr[j] * sc * w[j]);
}

// ---------------------------------------------------------------------------
// 64x128-tile GEMM (mlp1): XOR bank-swizzle on [*][64] LDS (round-14 proven).
// ---------------------------------------------------------------------------
__global__ __launch_bounds__(256) void gemm_bf_s(
    const bf16_t* __restrict__ A, const bf16_t* __restrict__ W,
    const float* __restrict__ bias, const float* __restrict__ add1,
    const float* __restrict__ add2, float* __restrict__ C,
    bf16_t* __restrict__ Cb,
    int M, int N, int K, int relu, int mode)
{
    __shared__ __align__(16) bf16_t As[64*64];
    __shared__ __align__(16) bf16_t Bs[128*64];
    const int tid = threadIdx.x;
    const int m0 = blockIdx.y * 64, n0 = blockIdx.x * 128;
    const int l = tid & 63, w = tid >> 6;
    const int wr = (w >> 1) * 32, wc = (w & 1) * 64;
    const int lr = l & 15, lk = (l >> 4) * 8;
    const int swz = (lr & 7) << 3;                     // read-side XOR (elems)

    const int srow = l >> 3;
    const int scolS = 8 * ((l & 7) ^ (l >> 3));        // pre-swizzled src col
    const bf16_t* Ag = A + (size_t)(m0 + w*16 + srow) * K + scolS;  // 2 slots/wave
    const bf16_t* Wg = W + (size_t)(n0 + w*32 + srow) * K + scolS;  // 4 slots/wave

    f32x4 z4 = {0.f, 0.f, 0.f, 0.f};
    f32x4 acc[2][4];
    #pragma unroll
    for (int i = 0; i < 2; ++i)
        #pragma unroll
        for (int j = 0; j < 4; ++j) acc[i][j] = z4;

    #pragma unroll
    for (int it = 0; it < 2; ++it)
        GLD16(Ag + (size_t)(it*8)*K, As + (w*2 + it)*512);
    #pragma unroll
    for (int it = 0; it < 4; ++it)
        GLD16(Wg + (size_t)(it*8)*K, Bs + (w*4 + it)*512);

    for (int k0 = 0; k0 < K; k0 += 64) {
        __syncthreads();                       // B1: tile landed
        bf16x8 afr[4], bfr[8];
        #pragma unroll
        for (int kk = 0; kk < 2; ++kk) {
            #pragma unroll
            for (int i = 0; i < 2; ++i)
                afr[kk*2+i] = *(const bf16x8*)&As[(wr + i*16 + lr)*64 + ((kk*32 + lk) ^ swz)];
            #pragma unroll
            for (int j = 0; j < 4; ++j)
                bfr[kk*4+j] = *(const bf16x8*)&Bs[(wc + j*16 + lr)*64 + ((kk*32 + lk) ^ swz)];
        }
        __syncthreads();                       // B2: reads done, LDS free
        if (k0 + 64 < K) {
            #pragma unroll
            for (int it = 0; it < 2; ++it)
                GLD16(Ag + (size_t)(it*8)*K + k0 + 64, As + (w*2 + it)*512);
            #pragma unroll
            for (int it = 0; it < 4; ++it)
                GLD16(Wg + (size_t)(it*8)*K + k0 + 64, Bs + (w*4 + it)*512);
        }
        #pragma unroll
        for (int kk = 0; kk < 2; ++kk)
            #pragma unroll
            for (int i = 0; i < 2; ++i)
                #pragma unroll
                for (int j = 0; j < 4; ++j)
                    acc[i][j] = MFMA16(afr[kk*2+i], bfr[kk*4+j], acc[i][j]);
    }

    #pragma unroll
    for (int i = 0; i < 2; ++i) {
        #pragma unroll
        for (int j = 0; j < 4; ++j) {
            const int col  = n0 + wc + j*16 + lr;
            const int row0 = m0 + wr + i*16 + (l >> 4)*4;
            const float bv = bias ? bias[col] : 0.f;
            #pragma unroll
            for (int r2 = 0; r2 < 4; ++r2) {
                const int row = row0 + r2;
                float val = acc[i][j][r2] + bv;
                if (add1) val += add1[(size_t)row*N + col];
                if (add2) val += add2[(size_t)row*N + col];
                if (relu) val = fmaxf(val, 0.f);
                if (mode == 0) C[(size_t)row*N + col] = val;
                else           Cb[(size_t)row*N + col] = (bf16_t)val;
            }
        }
    }
}

// ---------------------------------------------------------------------------
// 64x64-tile GEMM (o-proj, mlp2): BK=128 two-sub-buffer (round-15 proven).
// ---------------------------------------------------------------------------
__global__ __launch_bounds__(256) void gemm_bf_s64(
    const bf16_t* __restrict__ A, const bf16_t* __restrict__ W,
    const float* __restrict__ bias, const float* __restrict__ add1,
    const float* __restrict__ add2, float* __restrict__ C,
    int M, int N, int K)
{
    __shared__ __align__(16) bf16_t As[2][64*64];
    __shared__ __align__(16) bf16_t Bs[2][64*64];
    const int tid = threadIdx.x;
    // n-major XCD-chunked block swizzle (nwg = 512, % 8 == 0)
    const int nbx = gridDim.x, nby = gridDim.y;
    const int nwg = nbx * nby;
    const int lin = blockIdx.y * nbx + blockIdx.x;
    const int wg  = (lin & 7) * (nwg >> 3) + (lin >> 3);
    const int m0 = (wg % nby) * 64, n0 = (wg / nby) * 64;
    const int l = tid & 63, w = tid >> 6;
    const int wr = (w >> 1) * 32, wc = (w & 1) * 32;
    const int lr = l & 15, lk = (l >> 4) * 8;
    const int swz = (lr & 7) << 3;

    const int srow = l >> 3;
    const int scolS = 8 * ((l & 7) ^ (l >> 3));
    const bf16_t* Ag = A + (size_t)(m0 + w*16 + srow) * K + scolS;  // 2 slots/wave
    const bf16_t* Wg = W + (size_t)(n0 + w*16 + srow) * K + scolS;  // 2 slots/wave

    f32x4 z4 = {0.f, 0.f, 0.f, 0.f};
    f32x4 acc[2][2];
    #pragma unroll
    for (int i = 0; i < 2; ++i)
        #pragma unroll
        for (int j = 0; j < 2; ++j) acc[i][j] = z4;

    auto STAGE2 = [&](int k0) {
        #pragma unroll
        for (int hh = 0; hh < 2; ++hh)
            #pragma unroll
            for (int it = 0; it < 2; ++it) {
                GLD16(Ag + (size_t)(it*8)*K + k0 + hh*64, &As[hh][(w*2 + it)*512]);
                GLD16(Wg + (size_t)(it*8)*K + k0 + hh*64, &Bs[hh][(w*2 + it)*512]);
            }
    };

    STAGE2(0);
    for (int k0 = 0; k0 < K; k0 += 128) {
        __syncthreads();                       // B1: both sub-tiles landed
        bf16x8 afr[2][4], bfr[2][4];
        #pragma unroll
        for (int hh = 0; hh < 2; ++hh)
            #pragma unroll
            for (int kk = 0; kk < 2; ++kk)
                #pragma unroll
                for (int i = 0; i < 2; ++i) {
                    afr[hh][kk*2+i] = *(const bf16x8*)&As[hh][(wr + i*16 + lr)*64 + ((kk*32 + lk) ^ swz)];
                    bfr[hh][kk*2+i] = *(const bf16x8*)&Bs[hh][(wc + i*16 + lr)*64 + ((kk*32 + lk) ^ swz)];
                }
        __syncthreads();                       // B2: reads done, LDS free
        if (k0 + 128 < K) STAGE2(k0 + 128);
        #pragma unroll
        for (int hh = 0; hh < 2; ++hh)
            #pragma unroll
            for (int kk = 0; kk < 2; ++kk)
                #pragma unroll
                for (int i = 0; i < 2; ++i)
                    #pragma unroll
                    for (int j = 0; j < 2; ++j)
                        acc[i][j] = MFMA16(afr[hh][kk*2+i], bfr[hh][kk*2+j], acc[i][j]);
    }

    #pragma unroll
    for (int i = 0; i < 2; ++i) {
        #pragma unroll
        for (int j = 0; j < 2; ++j) {
            const int col  = n0 + wc + j*16 + lr;
            const int row0 = m0 + wr + i*16 + (l >> 4)*4;
            const float bv = bias ? bias[col] : 0.f;
            #pragma unroll
            for (int r2 = 0; r2 < 4; ++r2) {
                const int row = row0 + r2;
                float val = acc[i][j][r2] + bv;
                if (add1) val += add1[(size_t)row*N + col];
                if (add2) val += add2[(size_t)row*N + col];
                C[(size_t)row*N + col] = val;
            }
        }
    }
}

// ---------------------------------------------------------------------------
// 256x256 8-phase GEMM (T2 full swizzle + T3/T4 counted vmcnt + T5 setprio).
// Unchanged (bank conflicts == 0, race-free).
// ---------------------------------------------------------------------------
__global__ __launch_bounds__(512, 2) void gemm256_bf(
    const bf16_t* __restrict__ A, const bf16_t* __restrict__ W,
    float* __restrict__ C, int M, int N)
{
    extern __shared__ __align__(16) char dynsm[];
    bf16_t* TILE = (bf16_t*)dynsm;
    const int tid = threadIdx.x;
    const int nbx = gridDim.x, nby = gridDim.y;
    const int nwg = nbx * nby;
    const int lin = blockIdx.y * nbx + blockIdx.x;
    const int wg  = (lin & 7) * (nwg >> 3) + (lin >> 3);
    const int n0 = (wg / nby) * 256, m0 = (wg % nby) * 256;

    const int l = tid & 63, w = tid >> 6;
    const int wm = w >> 2, wn = w & 3;
    const int lr = l & 15, lg = l >> 4;
    const int swzr = ((l >> 1) & 7) << 3;
    const int srow = tid >> 3;
    const int scolE = ((tid & 7) * 8) ^ (((tid >> 4) & 7) << 3);

    const bf16_t* Ap = A + (size_t)m0 * 1024;
    const bf16_t* Wp = W + (size_t)n0 * 1024;

    auto STG = [&](int buf, int isB, int half, int k0) {
        const bf16_t* G = isB ? Wp : Ap;
        bf16_t* L = TILE + (buf*2 + isB)*16384 + half*8192 + w*512;
        const int rbase = half*128 + srow;
        GLD16(G + (size_t)rbase*1024 + k0 + scolE,          L);
        GLD16(G + (size_t)(rbase + 64)*1024 + k0 + scolE,   L + 4096);
    };
    auto RD_A = [&](int buf, int fi, int kk) -> bf16x8 {
        const int row = wm*128 + fi*16 + lr;
        return *(const bf16x8*)&TILE[(buf*2)*16384 + row*64 + ((kk*32 + lg*8) ^ swzr)];
    };
    auto RD_B = [&](int buf, int fj, int kk) -> bf16x8 {
        const int row = wn*64 + fj*16 + lr;
        return *(const bf16x8*)&TILE[(buf*2 + 1)*16384 + row*64 + ((kk*32 + lg*8) ^ swzr)];
    };

    f32x4 z4 = {0.f, 0.f, 0.f, 0.f};
    f32x4 acc[8][4];
    #pragma unroll
    for (int i = 0; i < 8; ++i)
        #pragma unroll
        for (int j = 0; j < 4; ++j) acc[i][j] = z4;
    bf16x8 bfr[4][2];

#define DO_PHASE(BUF, P, STAGE_STMT, TAIL_STMT) do {                          \
    bf16x8 a0_0 = RD_A(BUF, 2*(P), 0),   a0_1 = RD_A(BUF, 2*(P), 1);          \
    bf16x8 a1_0 = RD_A(BUF, 2*(P)+1, 0), a1_1 = RD_A(BUF, 2*(P)+1, 1);        \
    if ((P) == 0) {                                                           \
        _Pragma("unroll")                                                     \
        for (int fj = 0; fj < 4; ++fj) {                                      \
            bfr[fj][0] = RD_B(BUF, fj, 0);                                    \
            bfr[fj][1] = RD_B(BUF, fj, 1);                                    \
        }                                                                     \
    }                                                                         \
    STAGE_STMT;                                                               \
    BAR();                                                                    \
    __builtin_amdgcn_s_setprio(1);                                            \
    _Pragma("unroll")                                                         \
    for (int fj = 0; fj < 4; ++fj) {                                          \
        acc[2*(P)][fj]   = MFMA16(a0_0, bfr[fj][0], acc[2*(P)][fj]);          \
        acc[2*(P)][fj]   = MFMA16(a0_1, bfr[fj][1], acc[2*(P)][fj]);          \
        acc[2*(P)+1][fj] = MFMA16(a1_0, bfr[fj][0], acc[2*(P)+1][fj]);        \
        acc[2*(P)+1][fj] = MFMA16(a1_1, bfr[fj][1], acc[2*(P)+1][fj]);        \
    }                                                                         \
    __builtin_amdgcn_s_setprio(0);                                            \
    TAIL_STMT;                                                                \
    BAR();                                                                    \
} while (0)

    STG(0, 0, 0, 0);  STG(0, 0, 1, 0);
    STG(0, 1, 0, 0);  STG(0, 1, 1, 0);
    STG(1, 1, 0, 64); STG(1, 1, 1, 64);
    WAITVM(4);
    BAR();

    #pragma unroll 1
    for (int itr = 0; itr < 8; ++itr) {
        const int k_o  = (2*itr + 1) * 64;
        const int k_e2 = (2*itr + 2) * 64;
        const int k_o2 = (2*itr + 3) * 64;
        const bool more = (itr < 7);
        DO_PHASE(0, 0, STG(1, 0, 0, k_o), ;);
        DO_PHASE(0, 1, STG(1, 0, 1, k_o), ;);
        DO_PHASE(0, 2, if (more) STG(0, 1, 0, k_e2), ;);
        DO_PHASE(0, 3, if (more) STG(0, 1, 1, k_e2),
                 if (more) { WAITVM(4); } else { WAITVM(0); });
        DO_PHASE(1, 0, if (more) STG(0, 0, 0, k_e2), ;);
        DO_PHASE(1, 1, if (more) STG(0, 0, 1, k_e2), ;);
        DO_PHASE(1, 2, if (more) STG(1, 1, 0, k_o2), ;);
        DO_PHASE(1, 3, if (more) STG(1, 1, 1, k_o2),
                 if (more) { WAITVM(4); });
    }
#undef DO_PHASE

    #pragma unroll
    for (int i = 0; i < 8; ++i) {
        #pragma unroll
        for (int j = 0; j < 4; ++j) {
            const int col  = n0 + wn*64 + j*16 + lr;
            const int row0 = m0 + wm*128 + i*16 + lg*4;
            #pragma unroll
            for (int r2 = 0; r2 < 4; ++r2)
                C[(size_t)(row0 + r2)*N + col] = acc[i][j][r2];
        }
    }
}

// ---------------------------------------------------------------------------
// Fallback logits GEMM (A bf16 via gload_lds, W f32 reg-staged). Unchanged.
// ---------------------------------------------------------------------------
__global__ __launch_bounds__(256) void gemm_bfw32(
    const bf16_t* __restrict__ A, const float* __restrict__ W,
    float* __restrict__ C, int M, int N, int K)
{
    __shared__ __align__(16) bf16_t As[128*64];
    __shared__ __align__(16) bf16_t Bs[128*64];
    const int tid = threadIdx.x;
    const int m0 = blockIdx.y * 128, n0 = blockIdx.x * 128;
    const int l = tid & 63, w = tid >> 6;
    const int wr = (w >> 1) * 64, wc = (w & 1) * 64;
    const int lr = l & 15, lk = (l >> 4) * 8;
    const int srow = l >> 3, scol = (l & 7) * 8;
    const bf16_t* Ag = A + (size_t)(m0 + w*32 + srow) * K + scol;
    const int r = tid >> 1, half = (tid & 1) * 32;
    const float* Wp = W + (size_t)(n0 + r) * K + half;

    f32x4 z4 = {0.f, 0.f, 0.f, 0.f};
    f32x4 acc[4][4];
    #pragma unroll
    for (int i = 0; i < 4; ++i)
        #pragma unroll
        for (int j = 0; j < 4; ++j) acc[i][j] = z4;

    for (int k0 = 0; k0 < K; k0 += 64) {
        float4 wv[8];
        #pragma unroll
        for (int j = 0; j < 8; ++j) wv[j] = *(const float4*)(Wp + k0 + 4*j);
        __syncthreads();
        #pragma unroll
        for (int it = 0; it < 4; ++it)
            GLD16(Ag + (size_t)(it*8)*K + k0, As + (w*4 + it)*512);
        #pragma unroll
        for (int j = 0; j < 4; ++j)
            *(bf16x8*)&Bs[r*64 + half + 8*j] = pack8(wv[2*j], wv[2*j+1]);
        __syncthreads();
        #pragma unroll
        for (int kk = 0; kk < 2; ++kk) {
            bf16x8 afr[4], bfr[4];
            #pragma unroll
            for (int i = 0; i < 4; ++i)
                afr[i] = *(const bf16x8*)&As[(wr + i*16 + lr)*64 + kk*32 + lk];
            #pragma unroll
            for (int j = 0; j < 4; ++j)
                bfr[j] = *(const bf16x8*)&Bs[(wc + j*16 + lr)*64 + kk*32 + lk];
            #pragma unroll
            for (int i = 0; i < 4; ++i)
                #pragma unroll
                for (int j = 0; j < 4; ++j)
                    acc[i][j] = MFMA16(afr[i], bfr[j], acc[i][j]);
        }
    }
    #pragma unroll
    for (int i = 0; i < 4; ++i)
        #pragma unroll
        for (int j = 0; j < 4; ++j) {
            const int col  = n0 + wc + j*16 + lr;
            const int row0 = m0 + wr + i*16 + (l >> 4)*4;
            #pragma unroll
            for (int r2 = 0; r2 < 4; ++r2)
                C[(size_t)(row0 + r2)*N + col] = acc[i][j][r2];
        }
}

// ---------------------------------------------------------------------------
// Fused QKV GEMM, 64x128 tile, NEW BK=128 via two sub-buffers (16->8
// barrier iterations). XOR bank-swizzle on As/Bs per sub-buffer.
// seg 0=q (rope -> qbf), 1=k (rope + folded scaled_zero -> kbf),
// 2=v (-> Vt via LDS transpose [128][66], coalesced stores).
// ---------------------------------------------------------------------------
__global__ __launch_bounds__(256) void qkv_gemm(
    const bf16_t* __restrict__ A, const bf16_t* __restrict__ Wq,
    const bf16_t* __restrict__ Wk, const bf16_t* __restrict__ Wv,
    const float* __restrict__ qb, const float* __restrict__ vbias,
    const float* __restrict__ ctab, const float* __restrict__ stab,
    const float* __restrict__ fptr,
    bf16_t* __restrict__ qbf, bf16_t* __restrict__ kbf,
    bf16_t* __restrict__ vt, int S)
{
    // per sub-buffer: As = [0,4096) elems, Bs = [4096,12288).
    // tr (seg 2) reuses smem[0][0..8448) after the K-loop.
    __shared__ __align__(16) bf16_t smem[2][12288];
    const int tid = threadIdx.x;
    const int seg = blockIdx.x >> 3;              // 0=q 1=k 2=v
    const int n0  = (blockIdx.x & 7) * 128;       // col within segment
    const int m0  = blockIdx.y * 64;
    const bf16_t* W = (seg == 0) ? Wq : (seg == 1) ? Wk : Wv;
    const int K = DD;
    const int l = tid & 63, w = tid >> 6;
    const int wr = (w >> 1) * 32, wc = (w & 1) * 64;
    const int lr = l & 15, lk = (l >> 4) * 8;
    const int g4 = l >> 4;
    const int swz = (lr & 7) << 3;

    const int srow = l >> 3;
    const int scolS = 8 * ((l & 7) ^ (l >> 3));
    const bf16_t* Ag = A + (size_t)(m0 + w*16 + srow) * K + scolS;  // 2 slots/wave
    const bf16_t* Wg = W + (size_t)(n0 + w*32 + srow) * K + scolS;  // 4 slots/wave

    f32x4 z4 = {0.f, 0.f, 0.f, 0.f};
    f32x4 acc[2][4];
    #pragma unroll
    for (int i = 0; i < 2; ++i)
        #pragma unroll
        for (int j = 0; j < 4; ++j) acc[i][j] = z4;

    auto STAGE2 = [&](int k0) {
        #pragma unroll
        for (int hh = 0; hh < 2; ++hh) {
            #pragma unroll
            for (int it = 0; it < 2; ++it)
                GLD16(Ag + (size_t)(it*8)*K + k0 + hh*64, &smem[hh][(w*2 + it)*512]);
            #pragma unroll
            for (int it = 0; it < 4; ++it)
                GLD16(Wg + (size_t)(it*8)*K + k0 + hh*64, &smem[hh][4096 + (w*4 + it)*512]);
        }
    };

    STAGE2(0);
    for (int k0 = 0; k0 < K; k0 += 128) {
        __syncthreads();                       // B1: both sub-tiles landed
        bf16x8 afr[2][4], bfr[2][8];
        #pragma unroll
        for (int hh = 0; hh < 2; ++hh)
            #pragma unroll
            for (int kk = 0; kk < 2; ++kk) {
                #pragma unroll
                for (int i = 0; i < 2; ++i)
                    afr[hh][kk*2+i] = *(const bf16x8*)&smem[hh][(wr + i*16 + lr)*64 + ((kk*32 + lk) ^ swz)];
                #pragma unroll
                for (int j = 0; j < 4; ++j)
                    bfr[hh][kk*4+j] = *(const bf16x8*)&smem[hh][4096 + (wc + j*16 + lr)*64 + ((kk*32 + lk) ^ swz)];
            }
        __syncthreads();                       // B2: reads done, LDS free
        if (k0 + 128 < K) STAGE2(k0 + 128);
        #pragma unroll
        for (int hh = 0; hh < 2; ++hh)
            #pragma unroll
            for (int kk = 0; kk < 2; ++kk)
                #pragma unroll
                for (int i = 0; i < 2; ++i)
                    #pragma unroll
                    for (int j = 0; j < 4; ++j)
                        acc[i][j] = MFMA16(afr[hh][kk*2+i], bfr[hh][kk*4+j], acc[i][j]);
    }
    // last B2 drained all LDS reads -> safe to reuse smem as tr below

    float zf = 0.f;
    if (seg == 1) {
        float f = fptr[0];
        float sp = (f > 20.f) ? f : log1pf(expf(f));
        zf = fminf(fmaxf(sp, 1e-5f), 0.1f);
    }
    bf16_t* tr = &smem[0][0];                  // 128*66 = 8448 <= 12288

    #pragma unroll
    for (int i = 0; i < 2; ++i) {
        float ov[4][4];
        #pragma unroll
        for (int j = 0; j < 4; ++j) {
            const int col = n0 + wc + j*16 + lr;          // 0..1023 within seg
            const float bv = (seg == 0) ? qb[col] : (seg == 2) ? vbias[col] : 0.f;
            const int d  = col & 63;
            const int pi = d >> 1;
            #pragma unroll
            for (int r2 = 0; r2 < 4; ++r2) {
                const int row = m0 + wr + i*16 + g4*4 + r2;
                const int s  = row & (SEQ - 1);
                float val = acc[i][j][r2] + bv;
                if (seg < 2) {
                    // rope pair (even,odd) lives in lanes lr, lr^1
                    float partner = __shfl_xor(val, 1, 64);
                    float c  = ctab[s*32 + pi];
                    float sn = stab[s*32 + pi];
                    val = ((d & 1) == 0) ? (val*c - partner*sn)
                                         : (partner*sn + val*c);
                }
                ov[j][r2] = val;
            }
        }
        if (seg == 1) {
            // scaled_zero: d==0 value of each row held by lane (l&48), j=0
            #pragma unroll
            for (int r2 = 0; r2 < 4; ++r2) {
                float z0 = __shfl(ov[0][r2], (l & 48), 64);
                float zr = (z0 == 0.0f) ? zf : 1.0f;
                #pragma unroll
                for (int j = 0; j < 4; ++j) ov[j][r2] *= zr;
            }
        }
        #pragma unroll
        for (int j = 0; j < 4; ++j) {
            const int col = n0 + wc + j*16 + lr;
            #pragma unroll
            for (int r2 = 0; r2 < 4; ++r2) {
                const int row = m0 + wr + i*16 + g4*4 + r2;
                if (seg == 0)      qbf[(size_t)row*DD + col] = (bf16_t)ov[j][r2];
                else if (seg == 1) kbf[(size_t)row*DD + col] = (bf16_t)ov[j][r2];
                else tr[(col - n0)*66 + (row - m0)] = (bf16_t)ov[j][r2];
            }
        }
    }

    if (seg == 2) {
        __syncthreads();          // tr complete
        const int bb2 = m0 >> 10, s0 = m0 & (SEQ - 1);
        const int d2 = tid >> 1, sh = (tid & 1) * 32;
        const int hh2 = (n0 >> 6) + (d2 >> 6);
        const int dd2 = d2 & 63;
        bf16_t* dst = vt + ((size_t)(bb2*HEADS + hh2)*HDIM + dd2)*S + s0 + sh;
        const bf16_t* srcp = tr + d2*66 + sh;
        #pragma unroll
        for (int k2 = 0; k2 < 4; ++k2)
            *(bf16x8*)(dst + k2*8) = *(const bf16x8*)(srcp + k2*8);
    }
}

// ---------------------------------------------------------------------------
// Fused flash attention with XOR bank-swizzle on Ks/Vs/Ps (round-14 proven).
// Inline causal-tail V sum.
// ---------------------------------------------------------------------------
__global__ __launch_bounds__(256) void attn_fused(
    const bf16_t* __restrict__ qbf, const bf16_t* __restrict__ kbf,
    const bf16_t* __restrict__ Vt, bf16_t* __restrict__ O, int S)
{
    __shared__ __align__(16) bf16_t Ks[128*64];   // [k][64], swizzled
    __shared__ __align__(16) bf16_t Vs[64*128];   // [d][128], swizzled
    __shared__ __align__(16) bf16_t Ps[64*128];   // [q][128], XOR-swizzled

    const int tid = threadIdx.x;
    const int qt = (gridDim.x - 1) - blockIdx.x;  // heavy tiles dispatch first
    const int q0 = qt * 64;
    const int bh = blockIdx.y, b = bh >> 4, hh = bh & 15;
    const int l = tid & 63, w = tid >> 6;
    const int lr = l & 15, g = l >> 4;
    const int lk = g * 8;
    const int swz = (lr & 7) << 3;
    const int ktm = q0 >> 7;                 // last causal 128-key tile
    const int cnt = S - 128*(ktm + 1);       // fully-masked tail key count
    const int myq = q0 + w*16 + lr;          // q this lane holds stats for
    const int qloc = w*16 + lr;              // row in Ps

    bf16x8 qfr[2];
    {
        const bf16_t* qp = qbf + (size_t)(b*S + myq)*DD + hh*HDIM;
        qfr[0] = *(const bf16x8*)(qp + lk);
        qfr[1] = *(const bf16x8*)(qp + 32 + lk);
    }

    float m_run = (cnt > 0) ? 0.f : -3.0e38f;   // masked zeros participate
    float psum = 0.f;
    f32x4 z4 = {0.f, 0.f, 0.f, 0.f};
    f32x4 acc[4];                  // O[q = w*16 + g*4+r][d = j*16+lr]
    #pragma unroll
    for (int j = 0; j < 4; ++j) acc[j] = z4;

    const int sr = l >> 3;
    const int scK = 8 * ((l & 7) ^ (l >> 3));   // K-slot src col (8 rows x 64)
    // V-slot src col (4 rows x 128): row&7 = 4*(it&1)+g
    const int scV0 = (lr * 8) ^ ((4*0 + g) << 3);
    const int scV1 = (lr * 8) ^ ((4*1 + g) << 3);

    for (int kt = 0; kt <= ktm; ++kt) {
        __syncthreads();                       // Ks/Vs free from prev iter
        const bf16_t* Kg = kbf + (size_t)(b*S + kt*128)*DD + hh*HDIM;
        #pragma unroll
        for (int it = 0; it < 4; ++it) {
            const int krow = (w*4 + it)*8 + sr;
            GLD16(Kg + (size_t)krow*DD + scK, Ks + (w*4 + it)*512);
        }
        const bf16_t* Vg = Vt + ((size_t)bh*HDIM)*S + kt*128;
        #pragma unroll
        for (int it = 0; it < 4; ++it) {
            const int drow = (w*4 + it)*4 + g;
            GLD16(Vg + (size_t)drow*S + ((it & 1) ? scV1 : scV0),
                  Vs + (w*4 + it)*512);
        }
        __syncthreads();                       // tiles staged (vmcnt drained)

        float sv[8][4];
        float mtile = -3.0e38f;
        #pragma unroll
        for (int f = 0; f < 8; ++f) {
            bf16x8 ka0 = *(const bf16x8*)&Ks[(f*16 + lr)*64 + (lk ^ swz)];
            bf16x8 ka1 = *(const bf16x8*)&Ks[(f*16 + lr)*64 + ((32 + lk) ^ swz)];
            f32x4 t = z4;
            t = MFMA16(ka0, qfr[0], t);
            t = MFMA16(ka1, qfr[1], t);
            #pragma unroll
            for (int r = 0; r < 4; ++r) {
                const int key = kt*128 + f*16 + g*4 + r;
                float v = t[r] * 0.125f;       // HD^-0.5; zm folded into kbf
                v = (key <= myq) ? v : 0.f;
                sv[f][r] = v;
                mtile = fmaxf(mtile, v);
            }
        }
        mtile = fmaxf(mtile, __shfl_xor(mtile, 16, 64));
        mtile = fmaxf(mtile, __shfl_xor(mtile, 32, 64));
        const float m_new = fmaxf(m_run, mtile);
        const float fac = expf(m_run - m_new);
        m_run = m_new;

        float ps_t = 0.f;
        #pragma unroll
        for (int f = 0; f < 8; ++f) {
            bf16x4 pk;
            #pragma unroll
            for (int r = 0; r < 4; ++r) {
                float p = expf(sv[f][r] - m_new);
                ps_t += p;
                pk[r] = (bf16_t)p;
            }
            const int byteoff = (qloc*256 + f*32 + g*8) ^ ((lr & 7) << 4);
            *(bf16x4*)((char*)Ps + byteoff) = pk;
        }
        ps_t += __shfl_xor(ps_t, 16, 64);
        ps_t += __shfl_xor(ps_t, 32, 64);
        psum = psum * fac + ps_t;

        #pragma unroll
        for (int r = 0; r < 4; ++r) {
            const float fr_ = __shfl(fac, g*4 + r, 64);
            #pragma unroll
            for (int j = 0; j < 4; ++j) acc[j][r] *= fr_;
        }

        #pragma unroll
        for (int kk = 0; kk < 4; ++kk) {
            const int rboff = (qloc*256 + kk*64 + g*16) ^ ((lr & 7) << 4);
            bf16x8 pa = *(const bf16x8*)((char*)Ps + rboff);
            #pragma unroll
            for (int j = 0; j < 4; ++j) {
                bf16x8 vb = *(const bf16x8*)&Vs[(j*16 + lr)*128 + ((kk*32 + lk) ^ swz)];
                acc[j] = MFMA16(pa, vb, acc[j]);
            }
        }
    }

    // causal tail: sum_{k in tail} Vt[bh][d][k] per wave (lane l -> d=l)
    float vtail = 0.f;
    if (cnt > 0) {
        psum += (float)cnt * expf(-m_run);
        const bf16_t* vp = Vt + ((size_t)bh*HDIM + l)*S + 128*(ktm + 1);
        for (int k = 0; k < cnt; k += 8) {
            bf16x8 v = *(const bf16x8*)(vp + k);
            #pragma unroll
            for (int e = 0; e < 8; ++e) vtail += (float)v[e];
        }
    }

    #pragma unroll
    for (int r = 0; r < 4; ++r) {
        const float m_r  = __shfl(m_run, g*4 + r, 64);
        const float ps_r = __shfl(psum,  g*4 + r, 64);
        const float inv = 1.0f / ps_r;
        const float tailf = (cnt > 0) ? expf(-m_r) : 0.f;
        const int qrow = q0 + w*16 + g*4 + r;
        const size_t rowbase = (size_t)(b*S + qrow)*DD + hh*HDIM;
        #pragma unroll
        for (int j = 0; j < 4; ++j) {
            const float vt_j = __shfl(vtail, j*16 + lr, 64);
            float val = acc[j][r];
            if (cnt > 0) val += tailf * vt_j;
            O[rowbase + j*16 + lr] = (bf16_t)(val * inv);
        }
    }
}

// ---------------------------------------------------------------------------
extern "C" void kernel_launch(void* const* d_in, const int* in_sizes, int n_in,
                              void* d_out, int out_size, void* d_ws, size_t ws_size,
                              hipStream_t stream)
{
    const int S = SEQ;
    const int B = in_sizes[0] / S;     // 2
    const int M = B * S;               // 2048
    const int BH = B * HEADS;          // 32

    const int*   x       = (const int*)  d_in[0];
    const float* tok_emb = (const float*)d_in[2];
    const float* pos_emb = (const float*)d_in[3];
    const float* rif     = (const float*)d_in[4];
    const float* rbias   = (const float*)d_in[5];
    const float* brif    = (const float*)d_in[6];
    const float* bbias   = (const float*)d_in[7];
    const float* lna     = (const float*)d_in[8];
    const float* qw      = (const float*)d_in[9];
    const float* qb      = (const float*)d_in[10];
    const float* kw      = (const float*)d_in[11];
    const float* vw      = (const float*)d_in[12];
    const float* vbias   = (const float*)d_in[13];
    const float* ow      = (const float*)d_in[14];
    const float* ob      = (const float*)d_in[15];
    const float* factor  = (const float*)d_in[16];
    const float* lnc     = (const float*)d_in[17];
    const float* w1      = (const float*)d_in[18];
    const float* b1      = (const float*)d_in[19];
    const float* w2      = (const float*)d_in[20];
    const float* b2      = (const float*)d_in[21];
    const float* lnd     = (const float*)d_in[22];

    char* ob_ = (char*)d_out;
    const size_t MiB = 1024*1024;
    float*  h      = (float*)(ob_ + 0*MiB);      // 8 MiB
    float*  h2     = (float*)(ob_ + 8*MiB);      // 8 MiB
    bf16_t* qbf    = (bf16_t*)(ob_ + 16*MiB);    // 4 MiB
    bf16_t* kbf    = (bf16_t*)(ob_ + 20*MiB);    // 4 MiB
    bf16_t* vt     = (bf16_t*)(ob_ + 24*MiB);    // 4 MiB  Vt[b][h][d][S]
    bf16_t* attno  = (bf16_t*)(ob_ + 28*MiB);    // 4 MiB
    bf16_t* m1     = (bf16_t*)(ob_ + 32*MiB);    // 16 MiB
    float*  ctab   = (float*)(ob_ + 50*MiB);     // 128 KiB
    float*  stab   = (float*)(ob_ + 51*MiB);     // 128 KiB
    bf16_t* qw_bf  = (bf16_t*)(ob_ + 64*MiB);    // 8 MiB (4 layers)
    bf16_t* kw_bf  = (bf16_t*)(ob_ + 72*MiB);
    bf16_t* vw_bf  = (bf16_t*)(ob_ + 80*MiB);
    bf16_t* ow_bf  = (bf16_t*)(ob_ + 88*MiB);
    bf16_t* w1_bf  = (bf16_t*)(ob_ + 96*MiB);    // 32 MiB
    bf16_t* w2_bf  = (bf16_t*)(ob_ + 128*MiB);   // 32 MiB -> ends 160 < 250 MiB

    bf16_t* hn      = (bf16_t*)d_ws;             // 4 MiB
    bf16_t* temb_bf = (bf16_t*)((char*)d_ws + 4*MiB);
    const bool big_ws = ws_size >= (size_t)(70*MiB);

    // --- single batched weight conversion (all counts % 4096 == 0) ---
    {
        CvtBatch cb;
        const float* srcs[7] = {qw, kw, vw, ow, w1, w2, tok_emb};
        bf16_t*      dsts[7] = {qw_bf, kw_bf, vw_bf, ow_bf, w1_bf, w2_bf, temb_bf};
        const long   ns[7]   = {(long)NLAYER*DD*DD, (long)NLAYER*DD*DD,
                                (long)NLAYER*DD*DD, (long)NLAYER*DD*DD,
                                (long)NLAYER*FFDIM*DD, (long)NLAYER*FFDIM*DD,
                                (long)NVOCAB*DD};
        int nseg = big_ws ? 7 : 6;
        int acc = 0;
        for (int s = 0; s < 7; ++s) {
            cb.src[s] = srcs[s]; cb.dst[s] = dsts[s];
            cb.blk0[s] = acc;
            if (s < nseg) acc += (int)(ns[s] / 4096);
        }
        cb.nseg = nseg;
        cvt_batch<<<acc, 256, 0, stream>>>(cb);
    }
    ropetab_kernel<<<(S*32)/256, 256, 0, stream>>>(brif, bbias, ctab, stab);

    dim3 gMLP1(FFDIM/128, M/64);        // 32 x 32 = 1024 blocks (4/CU)
    dim3 gS64(DD/64,    M/64);          // 64x64-tile GEMMs: 512 blocks (2/CU)
    dim3 gV256(NVOCAB/256, M/256);      // 125 x 8 = 1000 blocks
    dim3 gVfb(NVOCAB/128, M/128);
    dim3 gQKV(3*8, M/64);               // 24 x 32 = 768 blocks (3/CU)
    dim3 gATT(S/64, BH);

    embed_rope_kernel<<<M, 512, 0, stream>>>(x, tok_emb, pos_emb, rif, rbias, h, S);

    for (int l = 0; l < NLAYER; ++l) {
        const size_t wo = (size_t)l * DD * DD;
        const size_t fo = (size_t)l * FFDIM * DD;
        rmsnorm_kernel<<<M, 256, 0, stream>>>(h, lna + l*DD, hn);
        qkv_gemm<<<gQKV, 256, 0, stream>>>(hn, qw_bf + wo, kw_bf + wo, vw_bf + wo,
                                           qb + l*DD, vbias + l*DD, ctab, stab,
                                           factor + l, qbf, kbf, vt, S);
        attn_fused<<<gATT, 256, 0, stream>>>(qbf, kbf, vt, attno, S);
        // h2 = attno @ ow^T + ob + h
        gemm_bf_s64<<<gS64, 256, 0, stream>>>(attno, ow_bf + wo, ob + l*DD, h, nullptr,
                                              h2, M, DD, DD);
        rmsnorm_kernel<<<M, 256, 0, stream>>>(h2, lnc + l*DD, hn);
        // m1 = relu(hn @ w1^T + b1), bf16 out
        gemm_bf_s<<<gMLP1, 256, 0, stream>>>(hn, w1_bf + fo, b1 + l*FFDIM, nullptr,
                                             nullptr, nullptr, m1, M, FFDIM, DD, 1, 1);
        // h_new = m1 @ w2^T + b2 + h2 + h   (== 2*h_old + attn + mlp)
        gemm_bf_s64<<<gS64, 256, 0, stream>>>(m1, w2_bf + fo, b2 + l*DD, h2, h,
                                              h, M, DD, FFDIM);
    }

    rmsnorm_kernel<<<M, 256, 0, stream>>>(h, lnd, hn);
    if (big_ws) {
        hipFuncSetAttribute((const void*)gemm256_bf,
                            hipFuncAttributeMaxDynamicSharedMemorySize, 131072);
        gemm256_bf<<<gV256, 512, 131072, stream>>>(hn, temb_bf, (float*)d_out,
                                                   M, NVOCAB);
    } else {
        gemm_bfw32<<<gVfb, 256, 0, stream>>>(hn, tok_emb, (float*)d_out, M, NVOCAB, DD);
    }
}

// Round 17
// 895.264 us; speedup vs baseline: 1.0038x; 1.0038x over previous
//
#include <hip/hip_runtime.h>
#include <hip/hip_bf16.h>

#define DD 1024
#define HEADS 16
#define HDIM 64
#define NLAYER 4
#define FFDIM 4096
#define NVOCAB 32000
#define SEQ 1024

typedef __bf16 bf16_t;
typedef __bf16 bf16x8 __attribute__((ext_vector_type(8)));
typedef __bf16 bf16x4 __attribute__((ext_vector_type(4)));
typedef float f32x4 __attribute__((ext_vector_type(4)));

#define MFMA16(a, b, c) __builtin_amdgcn_mfma_f32_16x16x32_bf16((a), (b), (c), 0, 0, 0)

// async global->LDS, 16B per lane, dest = wave-uniform base + lane*16
#define GLD16(gp, lp) \
    __builtin_amdgcn_global_load_lds( \
        (const __attribute__((address_space(1))) void*)(gp), \
        (__attribute__((address_space(3))) void*)(lp), 16, 0, 0)

// raw barrier (no implicit vmcnt/lgkm drain) with compile-time motion fences
#define BAR() do { __builtin_amdgcn_sched_barrier(0); \
                   __builtin_amdgcn_s_barrier(); \
                   __builtin_amdgcn_sched_barrier(0); } while (0)
#define WAITVM(n) asm volatile("s_waitcnt vmcnt(" #n ")" ::: "memory")

static __device__ __forceinline__ bf16x8 pack8(float4 u, float4 v) {
    bf16x8 r;
    r[0] = (bf16_t)u.x; r[1] = (bf16_t)u.y; r[2] = (bf16_t)u.z; r[3] = (bf16_t)u.w;
    r[4] = (bf16_t)v.x; r[5] = (bf16_t)v.y; r[6] = (bf16_t)v.z; r[7] = (bf16_t)v.w;
    return r;
}

// ---------------------------------------------------------------------------
// Batched f32 -> bf16 convert, 16 elems/thread. Segment counts % 4096 == 0.
// ---------------------------------------------------------------------------
struct CvtBatch {
    const float* src[7];
    bf16_t*      dst[7];
    int          blk0[7];   // starting block of each segment
    int          nseg;
};

__global__ __launch_bounds__(256) void cvt_batch(CvtBatch cb) {
    const int b = blockIdx.x;
    int s = 0;
    #pragma unroll
    for (int t = 1; t < 7; ++t)
        if (t < cb.nseg && b >= cb.blk0[t]) s = t;
    const long i = ((long)(b - cb.blk0[s]) * 256 + threadIdx.x) * 16;
    float4 a0 = *(const float4*)(cb.src[s] + i);
    float4 a1 = *(const float4*)(cb.src[s] + i + 4);
    float4 a2 = *(const float4*)(cb.src[s] + i + 8);
    float4 a3 = *(const float4*)(cb.src[s] + i + 12);
    *(bf16x8*)(cb.dst[s] + i)     = pack8(a0, a1);
    *(bf16x8*)(cb.dst[s] + i + 8) = pack8(a2, a3);
}

// ---------------------------------------------------------------------------
// Head-rope cos/sin tables: [S][32]
// ---------------------------------------------------------------------------
__global__ __launch_bounds__(256) void ropetab_kernel(
    const float* __restrict__ inv_freq, const float* __restrict__ rbias,
    float* __restrict__ ctab, float* __restrict__ stab)
{
    int idx = blockIdx.x * 256 + threadIdx.x;     // s*32 + i
    int s = idx >> 5, i = idx & 31;
    float fr = (float)s * inv_freq[i] + rbias[idx];
    ctab[idx] = cosf(fr);
    stab[idx] = sinf(fr);
}

// ---------------------------------------------------------------------------
// Embedding + decoder-level rotary
// ---------------------------------------------------------------------------
__global__ __launch_bounds__(512) void embed_rope_kernel(
    const int* __restrict__ x, const float* __restrict__ tok_emb,
    const float* __restrict__ pos_emb, const float* __restrict__ inv_freq,
    const float* __restrict__ rbias, float* __restrict__ h, int S)
{
    const int row = blockIdx.x;      // b*S + s
    const int s = row % S;
    const int i = threadIdx.x;       // 0..511 pair index
    const int tok = x[row];
    const float* e = tok_emb + (size_t)tok * DD;
    const float* p = pos_emb + (size_t)s * DD;
    float a = e[2*i]   + p[2*i];
    float b = e[2*i+1] + p[2*i+1];
    float fr = (float)s * inv_freq[i] + rbias[(size_t)s * (DD/2) + i];
    float c = cosf(fr), sn = sinf(fr);
    h[(size_t)row*DD + 2*i]   = a*c - b*sn;
    h[(size_t)row*DD + 2*i+1] = a*sn + b*c;
}

// ---------------------------------------------------------------------------
// RMSNorm with bf16 output
// ---------------------------------------------------------------------------
__global__ __launch_bounds__(256) void rmsnorm_kernel(
    const float* __restrict__ x, const float* __restrict__ w,
    bf16_t* __restrict__ y)
{
    const int row = blockIdx.x;
    const float* xr = x + (size_t)row * DD;
    float ss = 0.f;
    for (int j = threadIdx.x; j < DD; j += 256) { float v = xr[j]; ss += v*v; }
    for (int off = 32; off > 0; off >>= 1) ss += __shfl_down(ss, off, 64);
    __shared__ float r[4];
    if ((threadIdx.x & 63) == 0) r[threadIdx.x >> 6] = ss;
    __syncthreads();
    float tot = r[0] + r[1] + r[2] + r[3];
    float sc = rsqrtf(tot * (1.0f/(float)DD) + 1e-8f);
    for (int j = threadIdx.x; j < DD; j += 256)
        y[(size_t)row*DD + j] = (bf16_t)(xr[j] * sc * w[j]);
}

// ---------------------------------------------------------------------------
// 64x128-tile GEMM (mlp1): XOR bank-swizzle on [*][64] LDS (round-14 proven).
// ---------------------------------------------------------------------------
__global__ __launch_bounds__(256) void gemm_bf_s(
    const bf16_t* __restrict__ A, const bf16_t* __restrict__ W,
    const float* __restrict__ bias, const float* __restrict__ add1,
    const float* __restrict__ add2, float* __restrict__ C,
    bf16_t* __restrict__ Cb,
    int M, int N, int K, int relu, int mode)
{
    __shared__ __align__(16) bf16_t As[64*64];
    __shared__ __align__(16) bf16_t Bs[128*64];
    const int tid = threadIdx.x;
    const int m0 = blockIdx.y * 64, n0 = blockIdx.x * 128;
    const int l = tid & 63, w = tid >> 6;
    const int wr = (w >> 1) * 32, wc = (w & 1) * 64;
    const int lr = l & 15, lk = (l >> 4) * 8;
    const int swz = (lr & 7) << 3;                     // read-side XOR (elems)

    const int srow = l >> 3;
    const int scolS = 8 * ((l & 7) ^ (l >> 3));        // pre-swizzled src col
    const bf16_t* Ag = A + (size_t)(m0 + w*16 + srow) * K + scolS;  // 2 slots/wave
    const bf16_t* Wg = W + (size_t)(n0 + w*32 + srow) * K + scolS;  // 4 slots/wave

    f32x4 z4 = {0.f, 0.f, 0.f, 0.f};
    f32x4 acc[2][4];
    #pragma unroll
    for (int i = 0; i < 2; ++i)
        #pragma unroll
        for (int j = 0; j < 4; ++j) acc[i][j] = z4;

    #pragma unroll
    for (int it = 0; it < 2; ++it)
        GLD16(Ag + (size_t)(it*8)*K, As + (w*2 + it)*512);
    #pragma unroll
    for (int it = 0; it < 4; ++it)
        GLD16(Wg + (size_t)(it*8)*K, Bs + (w*4 + it)*512);

    for (int k0 = 0; k0 < K; k0 += 64) {
        __syncthreads();                       // B1: tile landed
        bf16x8 afr[4], bfr[8];
        #pragma unroll
        for (int kk = 0; kk < 2; ++kk) {
            #pragma unroll
            for (int i = 0; i < 2; ++i)
                afr[kk*2+i] = *(const bf16x8*)&As[(wr + i*16 + lr)*64 + ((kk*32 + lk) ^ swz)];
            #pragma unroll
            for (int j = 0; j < 4; ++j)
                bfr[kk*4+j] = *(const bf16x8*)&Bs[(wc + j*16 + lr)*64 + ((kk*32 + lk) ^ swz)];
        }
        __syncthreads();                       // B2: reads done, LDS free
        if (k0 + 64 < K) {
            #pragma unroll
            for (int it = 0; it < 2; ++it)
                GLD16(Ag + (size_t)(it*8)*K + k0 + 64, As + (w*2 + it)*512);
            #pragma unroll
            for (int it = 0; it < 4; ++it)
                GLD16(Wg + (size_t)(it*8)*K + k0 + 64, Bs + (w*4 + it)*512);
        }
        #pragma unroll
        for (int kk = 0; kk < 2; ++kk)
            #pragma unroll
            for (int i = 0; i < 2; ++i)
                #pragma unroll
                for (int j = 0; j < 4; ++j)
                    acc[i][j] = MFMA16(afr[kk*2+i], bfr[kk*4+j], acc[i][j]);
    }

    #pragma unroll
    for (int i = 0; i < 2; ++i) {
        #pragma unroll
        for (int j = 0; j < 4; ++j) {
            const int col  = n0 + wc + j*16 + lr;
            const int row0 = m0 + wr + i*16 + (l >> 4)*4;
            const float bv = bias ? bias[col] : 0.f;
            #pragma unroll
            for (int r2 = 0; r2 < 4; ++r2) {
                const int row = row0 + r2;
                float val = acc[i][j][r2] + bv;
                if (add1) val += add1[(size_t)row*N + col];
                if (add2) val += add2[(size_t)row*N + col];
                if (relu) val = fmaxf(val, 0.f);
                if (mode == 0) C[(size_t)row*N + col] = val;
                else           Cb[(size_t)row*N + col] = (bf16_t)val;
            }
        }
    }
}

// ---------------------------------------------------------------------------
// 64x64-tile GEMM (o-proj, mlp2): BK=128 two-sub-buffer (round-15 proven).
// ---------------------------------------------------------------------------
__global__ __launch_bounds__(256) void gemm_bf_s64(
    const bf16_t* __restrict__ A, const bf16_t* __restrict__ W,
    const float* __restrict__ bias, const float* __restrict__ add1,
    const float* __restrict__ add2, float* __restrict__ C,
    int M, int N, int K)
{
    __shared__ __align__(16) bf16_t As[2][64*64];
    __shared__ __align__(16) bf16_t Bs[2][64*64];
    const int tid = threadIdx.x;
    // n-major XCD-chunked block swizzle (nwg = 512, % 8 == 0)
    const int nbx = gridDim.x, nby = gridDim.y;
    const int nwg = nbx * nby;
    const int lin = blockIdx.y * nbx + blockIdx.x;
    const int wg  = (lin & 7) * (nwg >> 3) + (lin >> 3);
    const int m0 = (wg % nby) * 64, n0 = (wg / nby) * 64;
    const int l = tid & 63, w = tid >> 6;
    const int wr = (w >> 1) * 32, wc = (w & 1) * 32;
    const int lr = l & 15, lk = (l >> 4) * 8;
    const int swz = (lr & 7) << 3;

    const int srow = l >> 3;
    const int scolS = 8 * ((l & 7) ^ (l >> 3));
    const bf16_t* Ag = A + (size_t)(m0 + w*16 + srow) * K + scolS;  // 2 slots/wave
    const bf16_t* Wg = W + (size_t)(n0 + w*16 + srow) * K + scolS;  // 2 slots/wave

    f32x4 z4 = {0.f, 0.f, 0.f, 0.f};
    f32x4 acc[2][2];
    #pragma unroll
    for (int i = 0; i < 2; ++i)
        #pragma unroll
        for (int j = 0; j < 2; ++j) acc[i][j] = z4;

    auto STAGE2 = [&](int k0) {
        #pragma unroll
        for (int hh = 0; hh < 2; ++hh)
            #pragma unroll
            for (int it = 0; it < 2; ++it) {
                GLD16(Ag + (size_t)(it*8)*K + k0 + hh*64, &As[hh][(w*2 + it)*512]);
                GLD16(Wg + (size_t)(it*8)*K + k0 + hh*64, &Bs[hh][(w*2 + it)*512]);
            }
    };

    STAGE2(0);
    for (int k0 = 0; k0 < K; k0 += 128) {
        __syncthreads();                       // B1: both sub-tiles landed
        bf16x8 afr[2][4], bfr[2][4];
        #pragma unroll
        for (int hh = 0; hh < 2; ++hh)
            #pragma unroll
            for (int kk = 0; kk < 2; ++kk)
                #pragma unroll
                for (int i = 0; i < 2; ++i) {
                    afr[hh][kk*2+i] = *(const bf16x8*)&As[hh][(wr + i*16 + lr)*64 + ((kk*32 + lk) ^ swz)];
                    bfr[hh][kk*2+i] = *(const bf16x8*)&Bs[hh][(wc + i*16 + lr)*64 + ((kk*32 + lk) ^ swz)];
                }
        __syncthreads();                       // B2: reads done, LDS free
        if (k0 + 128 < K) STAGE2(k0 + 128);
        #pragma unroll
        for (int hh = 0; hh < 2; ++hh)
            #pragma unroll
            for (int kk = 0; kk < 2; ++kk)
                #pragma unroll
                for (int i = 0; i < 2; ++i)
                    #pragma unroll
                    for (int j = 0; j < 2; ++j)
                        acc[i][j] = MFMA16(afr[hh][kk*2+i], bfr[hh][kk*2+j], acc[i][j]);
    }

    #pragma unroll
    for (int i = 0; i < 2; ++i) {
        #pragma unroll
        for (int j = 0; j < 2; ++j) {
            const int col  = n0 + wc + j*16 + lr;
            const int row0 = m0 + wr + i*16 + (l >> 4)*4;
            const float bv = bias ? bias[col] : 0.f;
            #pragma unroll
            for (int r2 = 0; r2 < 4; ++r2) {
                const int row = row0 + r2;
                float val = acc[i][j][r2] + bv;
                if (add1) val += add1[(size_t)row*N + col];
                if (add2) val += add2[(size_t)row*N + col];
                C[(size_t)row*N + col] = val;
            }
        }
    }
}

// ---------------------------------------------------------------------------
// 256x256 8-phase GEMM (T2 full swizzle + T3/T4 counted vmcnt + T5 setprio).
// Unchanged (bank conflicts == 0, race-free).
// ---------------------------------------------------------------------------
__global__ __launch_bounds__(512, 2) void gemm256_bf(
    const bf16_t* __restrict__ A, const bf16_t* __restrict__ W,
    float* __restrict__ C, int M, int N)
{
    extern __shared__ __align__(16) char dynsm[];
    bf16_t* TILE = (bf16_t*)dynsm;
    const int tid = threadIdx.x;
    const int nbx = gridDim.x, nby = gridDim.y;
    const int nwg = nbx * nby;
    const int lin = blockIdx.y * nbx + blockIdx.x;
    const int wg  = (lin & 7) * (nwg >> 3) + (lin >> 3);
    const int n0 = (wg / nby) * 256, m0 = (wg % nby) * 256;

    const int l = tid & 63, w = tid >> 6;
    const int wm = w >> 2, wn = w & 3;
    const int lr = l & 15, lg = l >> 4;
    const int swzr = ((l >> 1) & 7) << 3;
    const int srow = tid >> 3;
    const int scolE = ((tid & 7) * 8) ^ (((tid >> 4) & 7) << 3);

    const bf16_t* Ap = A + (size_t)m0 * 1024;
    const bf16_t* Wp = W + (size_t)n0 * 1024;

    auto STG = [&](int buf, int isB, int half, int k0) {
        const bf16_t* G = isB ? Wp : Ap;
        bf16_t* L = TILE + (buf*2 + isB)*16384 + half*8192 + w*512;
        const int rbase = half*128 + srow;
        GLD16(G + (size_t)rbase*1024 + k0 + scolE,          L);
        GLD16(G + (size_t)(rbase + 64)*1024 + k0 + scolE,   L + 4096);
    };
    auto RD_A = [&](int buf, int fi, int kk) -> bf16x8 {
        const int row = wm*128 + fi*16 + lr;
        return *(const bf16x8*)&TILE[(buf*2)*16384 + row*64 + ((kk*32 + lg*8) ^ swzr)];
    };
    auto RD_B = [&](int buf, int fj, int kk) -> bf16x8 {
        const int row = wn*64 + fj*16 + lr;
        return *(const bf16x8*)&TILE[(buf*2 + 1)*16384 + row*64 + ((kk*32 + lg*8) ^ swzr)];
    };

    f32x4 z4 = {0.f, 0.f, 0.f, 0.f};
    f32x4 acc[8][4];
    #pragma unroll
    for (int i = 0; i < 8; ++i)
        #pragma unroll
        for (int j = 0; j < 4; ++j) acc[i][j] = z4;
    bf16x8 bfr[4][2];

#define DO_PHASE(BUF, P, STAGE_STMT, TAIL_STMT) do {                          \
    bf16x8 a0_0 = RD_A(BUF, 2*(P), 0),   a0_1 = RD_A(BUF, 2*(P), 1);          \
    bf16x8 a1_0 = RD_A(BUF, 2*(P)+1, 0), a1_1 = RD_A(BUF, 2*(P)+1, 1);        \
    if ((P) == 0) {                                                           \
        _Pragma("unroll")                                                     \
        for (int fj = 0; fj < 4; ++fj) {                                      \
            bfr[fj][0] = RD_B(BUF, fj, 0);                                    \
            bfr[fj][1] = RD_B(BUF, fj, 1);                                    \
        }                                                                     \
    }                                                                         \
    STAGE_STMT;                                                               \
    BAR();                                                                    \
    __builtin_amdgcn_s_setprio(1);                                            \
    _Pragma("unroll")                                                         \
    for (int fj = 0; fj < 4; ++fj) {                                          \
        acc[2*(P)][fj]   = MFMA16(a0_0, bfr[fj][0], acc[2*(P)][fj]);          \
        acc[2*(P)][fj]   = MFMA16(a0_1, bfr[fj][1], acc[2*(P)][fj]);          \
        acc[2*(P)+1][fj] = MFMA16(a1_0, bfr[fj][0], acc[2*(P)+1][fj]);        \
        acc[2*(P)+1][fj] = MFMA16(a1_1, bfr[fj][1], acc[2*(P)+1][fj]);        \
    }                                                                         \
    __builtin_amdgcn_s_setprio(0);                                            \
    TAIL_STMT;                                                                \
    BAR();                                                                    \
} while (0)

    STG(0, 0, 0, 0);  STG(0, 0, 1, 0);
    STG(0, 1, 0, 0);  STG(0, 1, 1, 0);
    STG(1, 1, 0, 64); STG(1, 1, 1, 64);
    WAITVM(4);
    BAR();

    #pragma unroll 1
    for (int itr = 0; itr < 8; ++itr) {
        const int k_o  = (2*itr + 1) * 64;
        const int k_e2 = (2*itr + 2) * 64;
        const int k_o2 = (2*itr + 3) * 64;
        const bool more = (itr < 7);
        DO_PHASE(0, 0, STG(1, 0, 0, k_o), ;);
        DO_PHASE(0, 1, STG(1, 0, 1, k_o), ;);
        DO_PHASE(0, 2, if (more) STG(0, 1, 0, k_e2), ;);
        DO_PHASE(0, 3, if (more) STG(0, 1, 1, k_e2),
                 if (more) { WAITVM(4); } else { WAITVM(0); });
        DO_PHASE(1, 0, if (more) STG(0, 0, 0, k_e2), ;);
        DO_PHASE(1, 1, if (more) STG(0, 0, 1, k_e2), ;);
        DO_PHASE(1, 2, if (more) STG(1, 1, 0, k_o2), ;);
        DO_PHASE(1, 3, if (more) STG(1, 1, 1, k_o2),
                 if (more) { WAITVM(4); });
    }
#undef DO_PHASE

    #pragma unroll
    for (int i = 0; i < 8; ++i) {
        #pragma unroll
        for (int j = 0; j < 4; ++j) {
            const int col  = n0 + wn*64 + j*16 + lr;
            const int row0 = m0 + wm*128 + i*16 + lg*4;
            #pragma unroll
            for (int r2 = 0; r2 < 4; ++r2)
                C[(size_t)(row0 + r2)*N + col] = acc[i][j][r2];
        }
    }
}

// ---------------------------------------------------------------------------
// Fallback logits GEMM (A bf16 via gload_lds, W f32 reg-staged). Unchanged.
// ---------------------------------------------------------------------------
__global__ __launch_bounds__(256) void gemm_bfw32(
    const bf16_t* __restrict__ A, const float* __restrict__ W,
    float* __restrict__ C, int M, int N, int K)
{
    __shared__ __align__(16) bf16_t As[128*64];
    __shared__ __align__(16) bf16_t Bs[128*64];
    const int tid = threadIdx.x;
    const int m0 = blockIdx.y * 128, n0 = blockIdx.x * 128;
    const int l = tid & 63, w = tid >> 6;
    const int wr = (w >> 1) * 64, wc = (w & 1) * 64;
    const int lr = l & 15, lk = (l >> 4) * 8;
    const int srow = l >> 3, scol = (l & 7) * 8;
    const bf16_t* Ag = A + (size_t)(m0 + w*32 + srow) * K + scol;
    const int r = tid >> 1, half = (tid & 1) * 32;
    const float* Wp = W + (size_t)(n0 + r) * K + half;

    f32x4 z4 = {0.f, 0.f, 0.f, 0.f};
    f32x4 acc[4][4];
    #pragma unroll
    for (int i = 0; i < 4; ++i)
        #pragma unroll
        for (int j = 0; j < 4; ++j) acc[i][j] = z4;

    for (int k0 = 0; k0 < K; k0 += 64) {
        float4 wv[8];
        #pragma unroll
        for (int j = 0; j < 8; ++j) wv[j] = *(const float4*)(Wp + k0 + 4*j);
        __syncthreads();
        #pragma unroll
        for (int it = 0; it < 4; ++it)
            GLD16(Ag + (size_t)(it*8)*K + k0, As + (w*4 + it)*512);
        #pragma unroll
        for (int j = 0; j < 4; ++j)
            *(bf16x8*)&Bs[r*64 + half + 8*j] = pack8(wv[2*j], wv[2*j+1]);
        __syncthreads();
        #pragma unroll
        for (int kk = 0; kk < 2; ++kk) {
            bf16x8 afr[4], bfr[4];
            #pragma unroll
            for (int i = 0; i < 4; ++i)
                afr[i] = *(const bf16x8*)&As[(wr + i*16 + lr)*64 + kk*32 + lk];
            #pragma unroll
            for (int j = 0; j < 4; ++j)
                bfr[j] = *(const bf16x8*)&Bs[(wc + j*16 + lr)*64 + kk*32 + lk];
            #pragma unroll
            for (int i = 0; i < 4; ++i)
                #pragma unroll
                for (int j = 0; j < 4; ++j)
                    acc[i][j] = MFMA16(afr[i], bfr[j], acc[i][j]);
        }
    }
    #pragma unroll
    for (int i = 0; i < 4; ++i)
        #pragma unroll
        for (int j = 0; j < 4; ++j) {
            const int col  = n0 + wc + j*16 + lr;
            const int row0 = m0 + wr + i*16 + (l >> 4)*4;
            #pragma unroll
            for (int r2 = 0; r2 < 4; ++r2)
                C[(size_t)(row0 + r2)*N + col] = acc[i][j][r2];
        }
}

// ---------------------------------------------------------------------------
// Fused QKV GEMM, 64x128 tile, BK=128 two-sub-buffer (round-16, neutral).
// seg 0=q (rope -> qbf), 1=k (rope + folded scaled_zero -> kbf),
// 2=v (-> Vt via LDS transpose [128][66], coalesced stores).
// ---------------------------------------------------------------------------
__global__ __launch_bounds__(256) void qkv_gemm(
    const bf16_t* __restrict__ A, const bf16_t* __restrict__ Wq,
    const bf16_t* __restrict__ Wk, const bf16_t* __restrict__ Wv,
    const float* __restrict__ qb, const float* __restrict__ vbias,
    const float* __restrict__ ctab, const float* __restrict__ stab,
    const float* __restrict__ fptr,
    bf16_t* __restrict__ qbf, bf16_t* __restrict__ kbf,
    bf16_t* __restrict__ vt, int S)
{
    // per sub-buffer: As = [0,4096) elems, Bs = [4096,12288).
    // tr (seg 2) reuses smem[0][0..8448) after the K-loop.
    __shared__ __align__(16) bf16_t smem[2][12288];
    const int tid = threadIdx.x;
    const int seg = blockIdx.x >> 3;              // 0=q 1=k 2=v
    const int n0  = (blockIdx.x & 7) * 128;       // col within segment
    const int m0  = blockIdx.y * 64;
    const bf16_t* W = (seg == 0) ? Wq : (seg == 1) ? Wk : Wv;
    const int K = DD;
    const int l = tid & 63, w = tid >> 6;
    const int wr = (w >> 1) * 32, wc = (w & 1) * 64;
    const int lr = l & 15, lk = (l >> 4) * 8;
    const int g4 = l >> 4;
    const int swz = (lr & 7) << 3;

    const int srow = l >> 3;
    const int scolS = 8 * ((l & 7) ^ (l >> 3));
    const bf16_t* Ag = A + (size_t)(m0 + w*16 + srow) * K + scolS;  // 2 slots/wave
    const bf16_t* Wg = W + (size_t)(n0 + w*32 + srow) * K + scolS;  // 4 slots/wave

    f32x4 z4 = {0.f, 0.f, 0.f, 0.f};
    f32x4 acc[2][4];
    #pragma unroll
    for (int i = 0; i < 2; ++i)
        #pragma unroll
        for (int j = 0; j < 4; ++j) acc[i][j] = z4;

    auto STAGE2 = [&](int k0) {
        #pragma unroll
        for (int hh = 0; hh < 2; ++hh) {
            #pragma unroll
            for (int it = 0; it < 2; ++it)
                GLD16(Ag + (size_t)(it*8)*K + k0 + hh*64, &smem[hh][(w*2 + it)*512]);
            #pragma unroll
            for (int it = 0; it < 4; ++it)
                GLD16(Wg + (size_t)(it*8)*K + k0 + hh*64, &smem[hh][4096 + (w*4 + it)*512]);
        }
    };

    STAGE2(0);
    for (int k0 = 0; k0 < K; k0 += 128) {
        __syncthreads();                       // B1: both sub-tiles landed
        bf16x8 afr[2][4], bfr[2][8];
        #pragma unroll
        for (int hh = 0; hh < 2; ++hh)
            #pragma unroll
            for (int kk = 0; kk < 2; ++kk) {
                #pragma unroll
                for (int i = 0; i < 2; ++i)
                    afr[hh][kk*2+i] = *(const bf16x8*)&smem[hh][(wr + i*16 + lr)*64 + ((kk*32 + lk) ^ swz)];
                #pragma unroll
                for (int j = 0; j < 4; ++j)
                    bfr[hh][kk*4+j] = *(const bf16x8*)&smem[hh][4096 + (wc + j*16 + lr)*64 + ((kk*32 + lk) ^ swz)];
            }
        __syncthreads();                       // B2: reads done, LDS free
        if (k0 + 128 < K) STAGE2(k0 + 128);
        #pragma unroll
        for (int hh = 0; hh < 2; ++hh)
            #pragma unroll
            for (int kk = 0; kk < 2; ++kk)
                #pragma unroll
                for (int i = 0; i < 2; ++i)
                    #pragma unroll
                    for (int j = 0; j < 4; ++j)
                        acc[i][j] = MFMA16(afr[hh][kk*2+i], bfr[hh][kk*4+j], acc[i][j]);
    }
    // last B2 drained all LDS reads -> safe to reuse smem as tr below

    float zf = 0.f;
    if (seg == 1) {
        float f = fptr[0];
        float sp = (f > 20.f) ? f : log1pf(expf(f));
        zf = fminf(fmaxf(sp, 1e-5f), 0.1f);
    }
    bf16_t* tr = &smem[0][0];                  // 128*66 = 8448 <= 12288

    #pragma unroll
    for (int i = 0; i < 2; ++i) {
        float ov[4][4];
        #pragma unroll
        for (int j = 0; j < 4; ++j) {
            const int col = n0 + wc + j*16 + lr;          // 0..1023 within seg
            const float bv = (seg == 0) ? qb[col] : (seg == 2) ? vbias[col] : 0.f;
            const int d  = col & 63;
            const int pi = d >> 1;
            #pragma unroll
            for (int r2 = 0; r2 < 4; ++r2) {
                const int row = m0 + wr + i*16 + g4*4 + r2;
                const int s  = row & (SEQ - 1);
                float val = acc[i][j][r2] + bv;
                if (seg < 2) {
                    // rope pair (even,odd) lives in lanes lr, lr^1
                    float partner = __shfl_xor(val, 1, 64);
                    float c  = ctab[s*32 + pi];
                    float sn = stab[s*32 + pi];
                    val = ((d & 1) == 0) ? (val*c - partner*sn)
                                         : (partner*sn + val*c);
                }
                ov[j][r2] = val;
            }
        }
        if (seg == 1) {
            // scaled_zero: d==0 value of each row held by lane (l&48), j=0
            #pragma unroll
            for (int r2 = 0; r2 < 4; ++r2) {
                float z0 = __shfl(ov[0][r2], (l & 48), 64);
                float zr = (z0 == 0.0f) ? zf : 1.0f;
                #pragma unroll
                for (int j = 0; j < 4; ++j) ov[j][r2] *= zr;
            }
        }
        #pragma unroll
        for (int j = 0; j < 4; ++j) {
            const int col = n0 + wc + j*16 + lr;
            #pragma unroll
            for (int r2 = 0; r2 < 4; ++r2) {
                const int row = m0 + wr + i*16 + g4*4 + r2;
                if (seg == 0)      qbf[(size_t)row*DD + col] = (bf16_t)ov[j][r2];
                else if (seg == 1) kbf[(size_t)row*DD + col] = (bf16_t)ov[j][r2];
                else tr[(col - n0)*66 + (row - m0)] = (bf16_t)ov[j][r2];
            }
        }
    }

    if (seg == 2) {
        __syncthreads();          // tr complete
        const int bb2 = m0 >> 10, s0 = m0 & (SEQ - 1);
        const int d2 = tid >> 1, sh = (tid & 1) * 32;
        const int hh2 = (n0 >> 6) + (d2 >> 6);
        const int dd2 = d2 & 63;
        bf16_t* dst = vt + ((size_t)(bb2*HEADS + hh2)*HDIM + dd2)*S + s0 + sh;
        const bf16_t* srcp = tr + d2*66 + sh;
        #pragma unroll
        for (int k2 = 0; k2 < 4; ++k2)
            *(bf16x8*)(dst + k2*8) = *(const bf16x8*)(srcp + k2*8);
    }
}

// ---------------------------------------------------------------------------
// Fused flash attention, NEW: two 128-key K/V tiles staged per barrier pair
// (Ks[2]/Vs[2], 80KB LDS = 2 blocks/CU, same as grid) -> barrier count
// halves; per-tile body identical to round-14 (same registers, same math).
// ---------------------------------------------------------------------------
__global__ __launch_bounds__(256) void attn_fused(
    const bf16_t* __restrict__ qbf, const bf16_t* __restrict__ kbf,
    const bf16_t* __restrict__ Vt, bf16_t* __restrict__ O, int S)
{
    __shared__ __align__(16) bf16_t Ks[2][128*64];   // [k][64], swizzled
    __shared__ __align__(16) bf16_t Vs[2][64*128];   // [d][128], swizzled
    __shared__ __align__(16) bf16_t Ps[64*128];      // [q][128], XOR-swizzled

    const int tid = threadIdx.x;
    const int qt = (gridDim.x - 1) - blockIdx.x;  // heavy tiles dispatch first
    const int q0 = qt * 64;
    const int bh = blockIdx.y, b = bh >> 4, hh = bh & 15;
    const int l = tid & 63, w = tid >> 6;
    const int lr = l & 15, g = l >> 4;
    const int lk = g * 8;
    const int swz = (lr & 7) << 3;
    const int ktm = q0 >> 7;                 // last causal 128-key tile
    const int cnt = S - 128*(ktm + 1);       // fully-masked tail key count
    const int myq = q0 + w*16 + lr;          // q this lane holds stats for
    const int qloc = w*16 + lr;              // row in Ps

    bf16x8 qfr[2];
    {
        const bf16_t* qp = qbf + (size_t)(b*S + myq)*DD + hh*HDIM;
        qfr[0] = *(const bf16x8*)(qp + lk);
        qfr[1] = *(const bf16x8*)(qp + 32 + lk);
    }

    float m_run = (cnt > 0) ? 0.f : -3.0e38f;   // masked zeros participate
    float psum = 0.f;
    f32x4 z4 = {0.f, 0.f, 0.f, 0.f};
    f32x4 acc[4];                  // O[q = w*16 + g*4+r][d = j*16+lr]
    #pragma unroll
    for (int j = 0; j < 4; ++j) acc[j] = z4;

    const int sr = l >> 3;
    const int scK = 8 * ((l & 7) ^ (l >> 3));   // K-slot src col (8 rows x 64)
    // V-slot src col (4 rows x 128): row&7 = 4*(it&1)+g
    const int scV0 = (lr * 8) ^ ((4*0 + g) << 3);
    const int scV1 = (lr * 8) ^ ((4*1 + g) << 3);

    auto STAGEKV = [&](int buf, int kt) {
        const bf16_t* Kg = kbf + (size_t)(b*S + kt*128)*DD + hh*HDIM;
        #pragma unroll
        for (int it = 0; it < 4; ++it) {
            const int krow = (w*4 + it)*8 + sr;
            GLD16(Kg + (size_t)krow*DD + scK, &Ks[buf][(w*4 + it)*512]);
        }
        const bf16_t* Vg = Vt + ((size_t)bh*HDIM)*S + kt*128;
        #pragma unroll
        for (int it = 0; it < 4; ++it) {
            const int drow = (w*4 + it)*4 + g;
            GLD16(Vg + (size_t)drow*S + ((it & 1) ? scV1 : scV0),
                  &Vs[buf][(w*4 + it)*512]);
        }
    };

    for (int kt0 = 0; kt0 <= ktm; kt0 += 2) {
        __syncthreads();                       // prev pair's reads done
        STAGEKV(0, kt0);
        if (kt0 + 1 <= ktm) STAGEKV(1, kt0 + 1);
        __syncthreads();                       // pair staged (vmcnt drained)

        #pragma unroll
        for (int half = 0; half < 2; ++half) {
            const int kt = kt0 + half;
            if (kt > ktm) continue;

            float sv[8][4];
            float mtile = -3.0e38f;
            #pragma unroll
            for (int f = 0; f < 8; ++f) {
                bf16x8 ka0 = *(const bf16x8*)&Ks[half][(f*16 + lr)*64 + (lk ^ swz)];
                bf16x8 ka1 = *(const bf16x8*)&Ks[half][(f*16 + lr)*64 + ((32 + lk) ^ swz)];
                f32x4 t = z4;
                t = MFMA16(ka0, qfr[0], t);
                t = MFMA16(ka1, qfr[1], t);
                #pragma unroll
                for (int r = 0; r < 4; ++r) {
                    const int key = kt*128 + f*16 + g*4 + r;
                    float v = t[r] * 0.125f;       // HD^-0.5; zm folded into kbf
                    v = (key <= myq) ? v : 0.f;
                    sv[f][r] = v;
                    mtile = fmaxf(mtile, v);
                }
            }
            mtile = fmaxf(mtile, __shfl_xor(mtile, 16, 64));
            mtile = fmaxf(mtile, __shfl_xor(mtile, 32, 64));
            const float m_new = fmaxf(m_run, mtile);
            const float fac = expf(m_run - m_new);
            m_run = m_new;

            float ps_t = 0.f;
            #pragma unroll
            for (int f = 0; f < 8; ++f) {
                bf16x4 pk;
                #pragma unroll
                for (int r = 0; r < 4; ++r) {
                    float p = expf(sv[f][r] - m_new);
                    ps_t += p;
                    pk[r] = (bf16_t)p;
                }
                const int byteoff = (qloc*256 + f*32 + g*8) ^ ((lr & 7) << 4);
                *(bf16x4*)((char*)Ps + byteoff) = pk;
            }
            ps_t += __shfl_xor(ps_t, 16, 64);
            ps_t += __shfl_xor(ps_t, 32, 64);
            psum = psum * fac + ps_t;

            #pragma unroll
            for (int r = 0; r < 4; ++r) {
                const float fr_ = __shfl(fac, g*4 + r, 64);
                #pragma unroll
                for (int j = 0; j < 4; ++j) acc[j][r] *= fr_;
            }

            #pragma unroll
            for (int kk = 0; kk < 4; ++kk) {
                const int rboff = (qloc*256 + kk*64 + g*16) ^ ((lr & 7) << 4);
                bf16x8 pa = *(const bf16x8*)((char*)Ps + rboff);
                #pragma unroll
                for (int j = 0; j < 4; ++j) {
                    bf16x8 vb = *(const bf16x8*)&Vs[half][(j*16 + lr)*128 + ((kk*32 + lk) ^ swz)];
                    acc[j] = MFMA16(pa, vb, acc[j]);
                }
            }
        }
    }

    // causal tail: sum_{k in tail} Vt[bh][d][k] per wave (lane l -> d=l)
    float vtail = 0.f;
    if (cnt > 0) {
        psum += (float)cnt * expf(-m_run);
        const bf16_t* vp = Vt + ((size_t)bh*HDIM + l)*S + 128*(ktm + 1);
        for (int k = 0; k < cnt; k += 8) {
            bf16x8 v = *(const bf16x8*)(vp + k);
            #pragma unroll
            for (int e = 0; e < 8; ++e) vtail += (float)v[e];
        }
    }

    #pragma unroll
    for (int r = 0; r < 4; ++r) {
        const float m_r  = __shfl(m_run, g*4 + r, 64);
        const float ps_r = __shfl(psum,  g*4 + r, 64);
        const float inv = 1.0f / ps_r;
        const float tailf = (cnt > 0) ? expf(-m_r) : 0.f;
        const int qrow = q0 + w*16 + g*4 + r;
        const size_t rowbase = (size_t)(b*S + qrow)*DD + hh*HDIM;
        #pragma unroll
        for (int j = 0; j < 4; ++j) {
            const float vt_j = __shfl(vtail, j*16 + lr, 64);
            float val = acc[j][r];
            if (cnt > 0) val += tailf * vt_j;
            O[rowbase + j*16 + lr] = (bf16_t)(val * inv);
        }
    }
}

// ---------------------------------------------------------------------------
extern "C" void kernel_launch(void* const* d_in, const int* in_sizes, int n_in,
                              void* d_out, int out_size, void* d_ws, size_t ws_size,
                              hipStream_t stream)
{
    const int S = SEQ;
    const int B = in_sizes[0] / S;     // 2
    const int M = B * S;               // 2048
    const int BH = B * HEADS;          // 32

    const int*   x       = (const int*)  d_in[0];
    const float* tok_emb = (const float*)d_in[2];
    const float* pos_emb = (const float*)d_in[3];
    const float* rif     = (const float*)d_in[4];
    const float* rbias   = (const float*)d_in[5];
    const float* brif    = (const float*)d_in[6];
    const float* bbias   = (const float*)d_in[7];
    const float* lna     = (const float*)d_in[8];
    const float* qw      = (const float*)d_in[9];
    const float* qb      = (const float*)d_in[10];
    const float* kw      = (const float*)d_in[11];
    const float* vw      = (const float*)d_in[12];
    const float* vbias   = (const float*)d_in[13];
    const float* ow      = (const float*)d_in[14];
    const float* ob      = (const float*)d_in[15];
    const float* factor  = (const float*)d_in[16];
    const float* lnc     = (const float*)d_in[17];
    const float* w1      = (const float*)d_in[18];
    const float* b1      = (const float*)d_in[19];
    const float* w2      = (const float*)d_in[20];
    const float* b2      = (const float*)d_in[21];
    const float* lnd     = (const float*)d_in[22];

    char* ob_ = (char*)d_out;
    const size_t MiB = 1024*1024;
    float*  h      = (float*)(ob_ + 0*MiB);      // 8 MiB
    float*  h2     = (float*)(ob_ + 8*MiB);      // 8 MiB
    bf16_t* qbf    = (bf16_t*)(ob_ + 16*MiB);    // 4 MiB
    bf16_t* kbf    = (bf16_t*)(ob_ + 20*MiB);    // 4 MiB
    bf16_t* vt     = (bf16_t*)(ob_ + 24*MiB);    // 4 MiB  Vt[b][h][d][S]
    bf16_t* attno  = (bf16_t*)(ob_ + 28*MiB);    // 4 MiB
    bf16_t* m1     = (bf16_t*)(ob_ + 32*MiB);    // 16 MiB
    float*  ctab   = (float*)(ob_ + 50*MiB);     // 128 KiB
    float*  stab   = (float*)(ob_ + 51*MiB);     // 128 KiB
    bf16_t* qw_bf  = (bf16_t*)(ob_ + 64*MiB);    // 8 MiB (4 layers)
    bf16_t* kw_bf  = (bf16_t*)(ob_ + 72*MiB);
    bf16_t* vw_bf  = (bf16_t*)(ob_ + 80*MiB);
    bf16_t* ow_bf  = (bf16_t*)(ob_ + 88*MiB);
    bf16_t* w1_bf  = (bf16_t*)(ob_ + 96*MiB);    // 32 MiB
    bf16_t* w2_bf  = (bf16_t*)(ob_ + 128*MiB);   // 32 MiB -> ends 160 < 250 MiB

    bf16_t* hn      = (bf16_t*)d_ws;             // 4 MiB
    bf16_t* temb_bf = (bf16_t*)((char*)d_ws + 4*MiB);
    const bool big_ws = ws_size >= (size_t)(70*MiB);

    // --- single batched weight conversion (all counts % 4096 == 0) ---
    {
        CvtBatch cb;
        const float* srcs[7] = {qw, kw, vw, ow, w1, w2, tok_emb};
        bf16_t*      dsts[7] = {qw_bf, kw_bf, vw_bf, ow_bf, w1_bf, w2_bf, temb_bf};
        const long   ns[7]   = {(long)NLAYER*DD*DD, (long)NLAYER*DD*DD,
                                (long)NLAYER*DD*DD, (long)NLAYER*DD*DD,
                                (long)NLAYER*FFDIM*DD, (long)NLAYER*FFDIM*DD,
                                (long)NVOCAB*DD};
        int nseg = big_ws ? 7 : 6;
        int acc = 0;
        for (int s = 0; s < 7; ++s) {
            cb.src[s] = srcs[s]; cb.dst[s] = dsts[s];
            cb.blk0[s] = acc;
            if (s < nseg) acc += (int)(ns[s] / 4096);
        }
        cb.nseg = nseg;
        cvt_batch<<<acc, 256, 0, stream>>>(cb);
    }
    ropetab_kernel<<<(S*32)/256, 256, 0, stream>>>(brif, bbias, ctab, stab);

    dim3 gMLP1(FFDIM/128, M/64);        // 32 x 32 = 1024 blocks (4/CU)
    dim3 gS64(DD/64,    M/64);          // 64x64-tile GEMMs: 512 blocks (2/CU)
    dim3 gV256(NVOCAB/256, M/256);      // 125 x 8 = 1000 blocks
    dim3 gVfb(NVOCAB/128, M/128);
    dim3 gQKV(3*8, M/64);               // 24 x 32 = 768 blocks (3/CU)
    dim3 gATT(S/64, BH);

    embed_rope_kernel<<<M, 512, 0, stream>>>(x, tok_emb, pos_emb, rif, rbias, h, S);

    for (int l = 0; l < NLAYER; ++l) {
        const size_t wo = (size_t)l * DD * DD;
        const size_t fo = (size_t)l * FFDIM * DD;
        rmsnorm_kernel<<<M, 256, 0, stream>>>(h, lna + l*DD, hn);
        qkv_gemm<<<gQKV, 256, 0, stream>>>(hn, qw_bf + wo, kw_bf + wo, vw_bf + wo,
                                           qb + l*DD, vbias + l*DD, ctab, stab,
                                           factor + l, qbf, kbf, vt, S);
        attn_fused<<<gATT, 256, 0, stream>>>(qbf, kbf, vt, attno, S);
        // h2 = attno @ ow^T + ob + h
        gemm_bf_s64<<<gS64, 256, 0, stream>>>(attno, ow_bf + wo, ob + l*DD, h, nullptr,
                                              h2, M, DD, DD);
        rmsnorm_kernel<<<M, 256, 0, stream>>>(h2, lnc + l*DD, hn);
        // m1 = relu(hn @ w1^T + b1), bf16 out
        gemm_bf_s<<<gMLP1, 256, 0, stream>>>(hn, w1_bf + fo, b1 + l*FFDIM, nullptr,
                                             nullptr, nullptr, m1, M, FFDIM, DD, 1, 1);
        // h_new = m1 @ w2^T + b2 + h2 + h   (== 2*h_old + attn + mlp)
        gemm_bf_s64<<<gS64, 256, 0, stream>>>(m1, w2_bf + fo, b2 + l*DD, h2, h,
                                              h, M, DD, FFDIM);
    }

    rmsnorm_kernel<<<M, 256, 0, stream>>>(h, lnd, hn);
    if (big_ws) {
        hipFuncSetAttribute((const void*)gemm256_bf,
                            hipFuncAttributeMaxDynamicSharedMemorySize, 131072);
        gemm256_bf<<<gV256, 512, 131072, stream>>>(hn, temb_bf, (float*)d_out,
                                                   M, NVOCAB);
    } else {
        gemm_bfw32<<<gVfb, 256, 0, stream>>>(hn, tok_emb, (float*)d_out, M, NVOCAB, DD);
    }
}

// Round 18
// 868.629 us; speedup vs baseline: 1.0345x; 1.0307x over previous
//
#include <hip/hip_runtime.h>
#include <hip/hip_bf16.h>

#define DD 1024
#define HEADS 16
#define HDIM 64
#define NLAYER 4
#define FFDIM 4096
#define NVOCAB 32000
#define SEQ 1024

typedef __bf16 bf16_t;
typedef __bf16 bf16x8 __attribute__((ext_vector_type(8)));
typedef __bf16 bf16x4 __attribute__((ext_vector_type(4)));
typedef __bf16 bf16x2 __attribute__((ext_vector_type(2)));
typedef float f32x4 __attribute__((ext_vector_type(4)));

#define MFMA16(a, b, c) __builtin_amdgcn_mfma_f32_16x16x32_bf16((a), (b), (c), 0, 0, 0)

// async global->LDS, 16B per lane, dest = wave-uniform base + lane*16
#define GLD16(gp, lp) \
    __builtin_amdgcn_global_load_lds( \
        (const __attribute__((address_space(1))) void*)(gp), \
        (__attribute__((address_space(3))) void*)(lp), 16, 0, 0)

// raw barrier (no implicit vmcnt/lgkm drain) with compile-time motion fences
#define BAR() do { __builtin_amdgcn_sched_barrier(0); \
                   __builtin_amdgcn_s_barrier(); \
                   __builtin_amdgcn_sched_barrier(0); } while (0)
#define WAITVM(n) asm volatile("s_waitcnt vmcnt(" #n ")" ::: "memory")

static __device__ __forceinline__ bf16x8 pack8(float4 u, float4 v) {
    bf16x8 r;
    r[0] = (bf16_t)u.x; r[1] = (bf16_t)u.y; r[2] = (bf16_t)u.z; r[3] = (bf16_t)u.w;
    r[4] = (bf16_t)v.x; r[5] = (bf16_t)v.y; r[6] = (bf16_t)v.z; r[7] = (bf16_t)v.w;
    return r;
}

// ---------------------------------------------------------------------------
// Batched f32 -> bf16 convert, 16 elems/thread. Segment counts % 4096 == 0.
// ---------------------------------------------------------------------------
struct CvtBatch {
    const float* src[7];
    bf16_t*      dst[7];
    int          blk0[7];   // starting block of each segment
    int          nseg;
};

__global__ __launch_bounds__(256) void cvt_batch(CvtBatch cb) {
    const int b = blockIdx.x;
    int s = 0;
    #pragma unroll
    for (int t = 1; t < 7; ++t)
        if (t < cb.nseg && b >= cb.blk0[t]) s = t;
    const long i = ((long)(b - cb.blk0[s]) * 256 + threadIdx.x) * 16;
    float4 a0 = *(const float4*)(cb.src[s] + i);
    float4 a1 = *(const float4*)(cb.src[s] + i + 4);
    float4 a2 = *(const float4*)(cb.src[s] + i + 8);
    float4 a3 = *(const float4*)(cb.src[s] + i + 12);
    *(bf16x8*)(cb.dst[s] + i)     = pack8(a0, a1);
    *(bf16x8*)(cb.dst[s] + i + 8) = pack8(a2, a3);
}

// ---------------------------------------------------------------------------
// Head-rope cos/sin tables: [S][32]
// ---------------------------------------------------------------------------
__global__ __launch_bounds__(256) void ropetab_kernel(
    const float* __restrict__ inv_freq, const float* __restrict__ rbias,
    float* __restrict__ ctab, float* __restrict__ stab)
{
    int idx = blockIdx.x * 256 + threadIdx.x;     // s*32 + i
    int s = idx >> 5, i = idx & 31;
    float fr = (float)s * inv_freq[i] + rbias[idx];
    ctab[idx] = cosf(fr);
    stab[idx] = sinf(fr);
}

// ---------------------------------------------------------------------------
// Embedding + decoder-level rotary; bf16 residual out (packed 2-elem store)
// ---------------------------------------------------------------------------
__global__ __launch_bounds__(512) void embed_rope_kernel(
    const int* __restrict__ x, const float* __restrict__ tok_emb,
    const float* __restrict__ pos_emb, const float* __restrict__ inv_freq,
    const float* __restrict__ rbias, bf16_t* __restrict__ h, int S)
{
    const int row = blockIdx.x;      // b*S + s
    const int s = row % S;
    const int i = threadIdx.x;       // 0..511 pair index
    const int tok = x[row];
    const float* e = tok_emb + (size_t)tok * DD;
    const float* p = pos_emb + (size_t)s * DD;
    float a = e[2*i]   + p[2*i];
    float b = e[2*i+1] + p[2*i+1];
    float fr = (float)s * inv_freq[i] + rbias[(size_t)s * (DD/2) + i];
    float c = cosf(fr), sn = sinf(fr);
    bf16x2 o;
    o[0] = (bf16_t)(a*c - b*sn);
    o[1] = (bf16_t)(a*sn + b*c);
    *(bf16x2*)(h + (size_t)row*DD + 2*i) = o;
}

// ---------------------------------------------------------------------------
// RMSNorm: bf16 in (vectorized x4), bf16 out
// ---------------------------------------------------------------------------
__global__ __launch_bounds__(256) void rmsnorm_kernel(
    const bf16_t* __restrict__ x, const float* __restrict__ w,
    bf16_t* __restrict__ y)
{
    const int row = blockIdx.x;
    const int j0 = threadIdx.x * 4;
    bf16x4 xv = *(const bf16x4*)(x + (size_t)row*DD + j0);
    float v0 = (float)xv[0], v1 = (float)xv[1], v2 = (float)xv[2], v3 = (float)xv[3];
    float ss = v0*v0 + v1*v1 + v2*v2 + v3*v3;
    for (int off = 32; off > 0; off >>= 1) ss += __shfl_down(ss, off, 64);
    __shared__ float r[4];
    if ((threadIdx.x & 63) == 0) r[threadIdx.x >> 6] = ss;
    __syncthreads();
    float tot = r[0] + r[1] + r[2] + r[3];
    float sc = rsqrtf(tot * (1.0f/(float)DD) + 1e-8f);
    bf16x4 o;
    o[0] = (bf16_t)(v0 * sc * w[j0 + 0]);
    o[1] = (bf16_t)(v1 * sc * w[j0 + 1]);
    o[2] = (bf16_t)(v2 * sc * w[j0 + 2]);
    o[3] = (bf16_t)(v3 * sc * w[j0 + 3]);
    *(bf16x4*)(y + (size_t)row*DD + j0) = o;
}

// ---------------------------------------------------------------------------
// 64x128-tile GEMM (mlp1): XOR bank-swizzle on [*][64] LDS (round-14 proven).
// ---------------------------------------------------------------------------
__global__ __launch_bounds__(256) void gemm_bf_s(
    const bf16_t* __restrict__ A, const bf16_t* __restrict__ W,
    const float* __restrict__ bias, float* __restrict__ C,
    bf16_t* __restrict__ Cb,
    int M, int N, int K, int relu, int mode)
{
    __shared__ __align__(16) bf16_t As[64*64];
    __shared__ __align__(16) bf16_t Bs[128*64];
    const int tid = threadIdx.x;
    const int m0 = blockIdx.y * 64, n0 = blockIdx.x * 128;
    const int l = tid & 63, w = tid >> 6;
    const int wr = (w >> 1) * 32, wc = (w & 1) * 64;
    const int lr = l & 15, lk = (l >> 4) * 8;
    const int swz = (lr & 7) << 3;                     // read-side XOR (elems)

    const int srow = l >> 3;
    const int scolS = 8 * ((l & 7) ^ (l >> 3));        // pre-swizzled src col
    const bf16_t* Ag = A + (size_t)(m0 + w*16 + srow) * K + scolS;  // 2 slots/wave
    const bf16_t* Wg = W + (size_t)(n0 + w*32 + srow) * K + scolS;  // 4 slots/wave

    f32x4 z4 = {0.f, 0.f, 0.f, 0.f};
    f32x4 acc[2][4];
    #pragma unroll
    for (int i = 0; i < 2; ++i)
        #pragma unroll
        for (int j = 0; j < 4; ++j) acc[i][j] = z4;

    #pragma unroll
    for (int it = 0; it < 2; ++it)
        GLD16(Ag + (size_t)(it*8)*K, As + (w*2 + it)*512);
    #pragma unroll
    for (int it = 0; it < 4; ++it)
        GLD16(Wg + (size_t)(it*8)*K, Bs + (w*4 + it)*512);

    for (int k0 = 0; k0 < K; k0 += 64) {
        __syncthreads();                       // B1: tile landed
        bf16x8 afr[4], bfr[8];
        #pragma unroll
        for (int kk = 0; kk < 2; ++kk) {
            #pragma unroll
            for (int i = 0; i < 2; ++i)
                afr[kk*2+i] = *(const bf16x8*)&As[(wr + i*16 + lr)*64 + ((kk*32 + lk) ^ swz)];
            #pragma unroll
            for (int j = 0; j < 4; ++j)
                bfr[kk*4+j] = *(const bf16x8*)&Bs[(wc + j*16 + lr)*64 + ((kk*32 + lk) ^ swz)];
        }
        __syncthreads();                       // B2: reads done, LDS free
        if (k0 + 64 < K) {
            #pragma unroll
            for (int it = 0; it < 2; ++it)
                GLD16(Ag + (size_t)(it*8)*K + k0 + 64, As + (w*2 + it)*512);
            #pragma unroll
            for (int it = 0; it < 4; ++it)
                GLD16(Wg + (size_t)(it*8)*K + k0 + 64, Bs + (w*4 + it)*512);
        }
        #pragma unroll
        for (int kk = 0; kk < 2; ++kk)
            #pragma unroll
            for (int i = 0; i < 2; ++i)
                #pragma unroll
                for (int j = 0; j < 4; ++j)
                    acc[i][j] = MFMA16(afr[kk*2+i], bfr[kk*4+j], acc[i][j]);
    }

    #pragma unroll
    for (int i = 0; i < 2; ++i) {
        #pragma unroll
        for (int j = 0; j < 4; ++j) {
            const int col  = n0 + wc + j*16 + lr;
            const int row0 = m0 + wr + i*16 + (l >> 4)*4;
            const float bv = bias ? bias[col] : 0.f;
            #pragma unroll
            for (int r2 = 0; r2 < 4; ++r2) {
                const int row = row0 + r2;
                float val = acc[i][j][r2] + bv;
                if (relu) val = fmaxf(val, 0.f);
                if (mode == 0) C[(size_t)row*N + col] = val;
                else           Cb[(size_t)row*N + col] = (bf16_t)val;
            }
        }
    }
}

// ---------------------------------------------------------------------------
// 64x64-tile GEMM (o-proj, mlp2): BK=128 two-sub-buffer (round-15 proven).
// NEW: bf16 residual adds (add1/add2) and bf16 output.
// ---------------------------------------------------------------------------
__global__ __launch_bounds__(256) void gemm_bf_s64(
    const bf16_t* __restrict__ A, const bf16_t* __restrict__ W,
    const float* __restrict__ bias, const bf16_t* __restrict__ add1,
    const bf16_t* __restrict__ add2, bf16_t* __restrict__ C,
    int M, int N, int K)
{
    __shared__ __align__(16) bf16_t As[2][64*64];
    __shared__ __align__(16) bf16_t Bs[2][64*64];
    const int tid = threadIdx.x;
    // n-major XCD-chunked block swizzle (nwg = 512, % 8 == 0)
    const int nbx = gridDim.x, nby = gridDim.y;
    const int nwg = nbx * nby;
    const int lin = blockIdx.y * nbx + blockIdx.x;
    const int wg  = (lin & 7) * (nwg >> 3) + (lin >> 3);
    const int m0 = (wg % nby) * 64, n0 = (wg / nby) * 64;
    const int l = tid & 63, w = tid >> 6;
    const int wr = (w >> 1) * 32, wc = (w & 1) * 32;
    const int lr = l & 15, lk = (l >> 4) * 8;
    const int swz = (lr & 7) << 3;

    const int srow = l >> 3;
    const int scolS = 8 * ((l & 7) ^ (l >> 3));
    const bf16_t* Ag = A + (size_t)(m0 + w*16 + srow) * K + scolS;  // 2 slots/wave
    const bf16_t* Wg = W + (size_t)(n0 + w*16 + srow) * K + scolS;  // 2 slots/wave

    f32x4 z4 = {0.f, 0.f, 0.f, 0.f};
    f32x4 acc[2][2];
    #pragma unroll
    for (int i = 0; i < 2; ++i)
        #pragma unroll
        for (int j = 0; j < 2; ++j) acc[i][j] = z4;

    auto STAGE2 = [&](int k0) {
        #pragma unroll
        for (int hh = 0; hh < 2; ++hh)
            #pragma unroll
            for (int it = 0; it < 2; ++it) {
                GLD16(Ag + (size_t)(it*8)*K + k0 + hh*64, &As[hh][(w*2 + it)*512]);
                GLD16(Wg + (size_t)(it*8)*K + k0 + hh*64, &Bs[hh][(w*2 + it)*512]);
            }
    };

    STAGE2(0);
    for (int k0 = 0; k0 < K; k0 += 128) {
        __syncthreads();                       // B1: both sub-tiles landed
        bf16x8 afr[2][4], bfr[2][4];
        #pragma unroll
        for (int hh = 0; hh < 2; ++hh)
            #pragma unroll
            for (int kk = 0; kk < 2; ++kk)
                #pragma unroll
                for (int i = 0; i < 2; ++i) {
                    afr[hh][kk*2+i] = *(const bf16x8*)&As[hh][(wr + i*16 + lr)*64 + ((kk*32 + lk) ^ swz)];
                    bfr[hh][kk*2+i] = *(const bf16x8*)&Bs[hh][(wc + i*16 + lr)*64 + ((kk*32 + lk) ^ swz)];
                }
        __syncthreads();                       // B2: reads done, LDS free
        if (k0 + 128 < K) STAGE2(k0 + 128);
        #pragma unroll
        for (int hh = 0; hh < 2; ++hh)
            #pragma unroll
            for (int kk = 0; kk < 2; ++kk)
                #pragma unroll
                for (int i = 0; i < 2; ++i)
                    #pragma unroll
                    for (int j = 0; j < 2; ++j)
                        acc[i][j] = MFMA16(afr[hh][kk*2+i], bfr[hh][kk*2+j], acc[i][j]);
    }

    #pragma unroll
    for (int i = 0; i < 2; ++i) {
        #pragma unroll
        for (int j = 0; j < 2; ++j) {
            const int col  = n0 + wc + j*16 + lr;
            const int row0 = m0 + wr + i*16 + (l >> 4)*4;
            const float bv = bias ? bias[col] : 0.f;
            #pragma unroll
            for (int r2 = 0; r2 < 4; ++r2) {
                const int row = row0 + r2;
                float val = acc[i][j][r2] + bv;
                if (add1) val += (float)add1[(size_t)row*N + col];
                if (add2) val += (float)add2[(size_t)row*N + col];
                C[(size_t)row*N + col] = (bf16_t)val;
            }
        }
    }
}

// ---------------------------------------------------------------------------
// 256x256 8-phase GEMM (T2 full swizzle + T3/T4 counted vmcnt + T5 setprio).
// Unchanged (bank conflicts == 0, race-free).
// ---------------------------------------------------------------------------
__global__ __launch_bounds__(512, 2) void gemm256_bf(
    const bf16_t* __restrict__ A, const bf16_t* __restrict__ W,
    float* __restrict__ C, int M, int N)
{
    extern __shared__ __align__(16) char dynsm[];
    bf16_t* TILE = (bf16_t*)dynsm;
    const int tid = threadIdx.x;
    const int nbx = gridDim.x, nby = gridDim.y;
    const int nwg = nbx * nby;
    const int lin = blockIdx.y * nbx + blockIdx.x;
    const int wg  = (lin & 7) * (nwg >> 3) + (lin >> 3);
    const int n0 = (wg / nby) * 256, m0 = (wg % nby) * 256;

    const int l = tid & 63, w = tid >> 6;
    const int wm = w >> 2, wn = w & 3;
    const int lr = l & 15, lg = l >> 4;
    const int swzr = ((l >> 1) & 7) << 3;
    const int srow = tid >> 3;
    const int scolE = ((tid & 7) * 8) ^ (((tid >> 4) & 7) << 3);

    const bf16_t* Ap = A + (size_t)m0 * 1024;
    const bf16_t* Wp = W + (size_t)n0 * 1024;

    auto STG = [&](int buf, int isB, int half, int k0) {
        const bf16_t* G = isB ? Wp : Ap;
        bf16_t* L = TILE + (buf*2 + isB)*16384 + half*8192 + w*512;
        const int rbase = half*128 + srow;
        GLD16(G + (size_t)rbase*1024 + k0 + scolE,          L);
        GLD16(G + (size_t)(rbase + 64)*1024 + k0 + scolE,   L + 4096);
    };
    auto RD_A = [&](int buf, int fi, int kk) -> bf16x8 {
        const int row = wm*128 + fi*16 + lr;
        return *(const bf16x8*)&TILE[(buf*2)*16384 + row*64 + ((kk*32 + lg*8) ^ swzr)];
    };
    auto RD_B = [&](int buf, int fj, int kk) -> bf16x8 {
        const int row = wn*64 + fj*16 + lr;
        return *(const bf16x8*)&TILE[(buf*2 + 1)*16384 + row*64 + ((kk*32 + lg*8) ^ swzr)];
    };

    f32x4 z4 = {0.f, 0.f, 0.f, 0.f};
    f32x4 acc[8][4];
    #pragma unroll
    for (int i = 0; i < 8; ++i)
        #pragma unroll
        for (int j = 0; j < 4; ++j) acc[i][j] = z4;
    bf16x8 bfr[4][2];

#define DO_PHASE(BUF, P, STAGE_STMT, TAIL_STMT) do {                          \
    bf16x8 a0_0 = RD_A(BUF, 2*(P), 0),   a0_1 = RD_A(BUF, 2*(P), 1);          \
    bf16x8 a1_0 = RD_A(BUF, 2*(P)+1, 0), a1_1 = RD_A(BUF, 2*(P)+1, 1);        \
    if ((P) == 0) {                                                           \
        _Pragma("unroll")                                                     \
        for (int fj = 0; fj < 4; ++fj) {                                      \
            bfr[fj][0] = RD_B(BUF, fj, 0);                                    \
            bfr[fj][1] = RD_B(BUF, fj, 1);                                    \
        }                                                                     \
    }                                                                         \
    STAGE_STMT;                                                               \
    BAR();                                                                    \
    __builtin_amdgcn_s_setprio(1);                                            \
    _Pragma("unroll")                                                         \
    for (int fj = 0; fj < 4; ++fj) {                                          \
        acc[2*(P)][fj]   = MFMA16(a0_0, bfr[fj][0], acc[2*(P)][fj]);          \
        acc[2*(P)][fj]   = MFMA16(a0_1, bfr[fj][1], acc[2*(P)][fj]);          \
        acc[2*(P)+1][fj] = MFMA16(a1_0, bfr[fj][0], acc[2*(P)+1][fj]);        \
        acc[2*(P)+1][fj] = MFMA16(a1_1, bfr[fj][1], acc[2*(P)+1][fj]);        \
    }                                                                         \
    __builtin_amdgcn_s_setprio(0);                                            \
    TAIL_STMT;                                                                \
    BAR();                                                                    \
} while (0)

    STG(0, 0, 0, 0);  STG(0, 0, 1, 0);
    STG(0, 1, 0, 0);  STG(0, 1, 1, 0);
    STG(1, 1, 0, 64); STG(1, 1, 1, 64);
    WAITVM(4);
    BAR();

    #pragma unroll 1
    for (int itr = 0; itr < 8; ++itr) {
        const int k_o  = (2*itr + 1) * 64;
        const int k_e2 = (2*itr + 2) * 64;
        const int k_o2 = (2*itr + 3) * 64;
        const bool more = (itr < 7);
        DO_PHASE(0, 0, STG(1, 0, 0, k_o), ;);
        DO_PHASE(0, 1, STG(1, 0, 1, k_o), ;);
        DO_PHASE(0, 2, if (more) STG(0, 1, 0, k_e2), ;);
        DO_PHASE(0, 3, if (more) STG(0, 1, 1, k_e2),
                 if (more) { WAITVM(4); } else { WAITVM(0); });
        DO_PHASE(1, 0, if (more) STG(0, 0, 0, k_e2), ;);
        DO_PHASE(1, 1, if (more) STG(0, 0, 1, k_e2), ;);
        DO_PHASE(1, 2, if (more) STG(1, 1, 0, k_o2), ;);
        DO_PHASE(1, 3, if (more) STG(1, 1, 1, k_o2),
                 if (more) { WAITVM(4); });
    }
#undef DO_PHASE

    #pragma unroll
    for (int i = 0; i < 8; ++i) {
        #pragma unroll
        for (int j = 0; j < 4; ++j) {
            const int col  = n0 + wn*64 + j*16 + lr;
            const int row0 = m0 + wm*128 + i*16 + lg*4;
            #pragma unroll
            for (int r2 = 0; r2 < 4; ++r2)
                C[(size_t)(row0 + r2)*N + col] = acc[i][j][r2];
        }
    }
}

// ---------------------------------------------------------------------------
// Fallback logits GEMM (A bf16 via gload_lds, W f32 reg-staged). Unchanged.
// ---------------------------------------------------------------------------
__global__ __launch_bounds__(256) void gemm_bfw32(
    const bf16_t* __restrict__ A, const float* __restrict__ W,
    float* __restrict__ C, int M, int N, int K)
{
    __shared__ __align__(16) bf16_t As[128*64];
    __shared__ __align__(16) bf16_t Bs[128*64];
    const int tid = threadIdx.x;
    const int m0 = blockIdx.y * 128, n0 = blockIdx.x * 128;
    const int l = tid & 63, w = tid >> 6;
    const int wr = (w >> 1) * 64, wc = (w & 1) * 64;
    const int lr = l & 15, lk = (l >> 4) * 8;
    const int srow = l >> 3, scol = (l & 7) * 8;
    const bf16_t* Ag = A + (size_t)(m0 + w*32 + srow) * K + scol;
    const int r = tid >> 1, half = (tid & 1) * 32;
    const float* Wp = W + (size_t)(n0 + r) * K + half;

    f32x4 z4 = {0.f, 0.f, 0.f, 0.f};
    f32x4 acc[4][4];
    #pragma unroll
    for (int i = 0; i < 4; ++i)
        #pragma unroll
        for (int j = 0; j < 4; ++j) acc[i][j] = z4;

    for (int k0 = 0; k0 < K; k0 += 64) {
        float4 wv[8];
        #pragma unroll
        for (int j = 0; j < 8; ++j) wv[j] = *(const float4*)(Wp + k0 + 4*j);
        __syncthreads();
        #pragma unroll
        for (int it = 0; it < 4; ++it)
            GLD16(Ag + (size_t)(it*8)*K + k0, As + (w*4 + it)*512);
        #pragma unroll
        for (int j = 0; j < 4; ++j)
            *(bf16x8*)&Bs[r*64 + half + 8*j] = pack8(wv[2*j], wv[2*j+1]);
        __syncthreads();
        #pragma unroll
        for (int kk = 0; kk < 2; ++kk) {
            bf16x8 afr[4], bfr[4];
            #pragma unroll
            for (int i = 0; i < 4; ++i)
                afr[i] = *(const bf16x8*)&As[(wr + i*16 + lr)*64 + kk*32 + lk];
            #pragma unroll
            for (int j = 0; j < 4; ++j)
                bfr[j] = *(const bf16x8*)&Bs[(wc + j*16 + lr)*64 + kk*32 + lk];
            #pragma unroll
            for (int i = 0; i < 4; ++i)
                #pragma unroll
                for (int j = 0; j < 4; ++j)
                    acc[i][j] = MFMA16(afr[i], bfr[j], acc[i][j]);
        }
    }
    #pragma unroll
    for (int i = 0; i < 4; ++i)
        #pragma unroll
        for (int j = 0; j < 4; ++j) {
            const int col  = n0 + wc + j*16 + lr;
            const int row0 = m0 + wr + i*16 + (l >> 4)*4;
            #pragma unroll
            for (int r2 = 0; r2 < 4; ++r2)
                C[(size_t)(row0 + r2)*N + col] = acc[i][j][r2];
        }
}

// ---------------------------------------------------------------------------
// Fused QKV GEMM, 64x128 tile, BK=128 two-sub-buffer.
// seg 0=q (rope -> qbf), 1=k (rope + folded scaled_zero -> kbf),
// 2=v (-> Vt via LDS transpose [128][66], coalesced stores).
// ---------------------------------------------------------------------------
__global__ __launch_bounds__(256) void qkv_gemm(
    const bf16_t* __restrict__ A, const bf16_t* __restrict__ Wq,
    const bf16_t* __restrict__ Wk, const bf16_t* __restrict__ Wv,
    const float* __restrict__ qb, const float* __restrict__ vbias,
    const float* __restrict__ ctab, const float* __restrict__ stab,
    const float* __restrict__ fptr,
    bf16_t* __restrict__ qbf, bf16_t* __restrict__ kbf,
    bf16_t* __restrict__ vt, int S)
{
    // per sub-buffer: As = [0,4096) elems, Bs = [4096,12288).
    // tr (seg 2) reuses smem[0][0..8448) after the K-loop.
    __shared__ __align__(16) bf16_t smem[2][12288];
    const int tid = threadIdx.x;
    const int seg = blockIdx.x >> 3;              // 0=q 1=k 2=v
    const int n0  = (blockIdx.x & 7) * 128;       // col within segment
    const int m0  = blockIdx.y * 64;
    const bf16_t* W = (seg == 0) ? Wq : (seg == 1) ? Wk : Wv;
    const int K = DD;
    const int l = tid & 63, w = tid >> 6;
    const int wr = (w >> 1) * 32, wc = (w & 1) * 64;
    const int lr = l & 15, lk = (l >> 4) * 8;
    const int g4 = l >> 4;
    const int swz = (lr & 7) << 3;

    const int srow = l >> 3;
    const int scolS = 8 * ((l & 7) ^ (l >> 3));
    const bf16_t* Ag = A + (size_t)(m0 + w*16 + srow) * K + scolS;  // 2 slots/wave
    const bf16_t* Wg = W + (size_t)(n0 + w*32 + srow) * K + scolS;  // 4 slots/wave

    f32x4 z4 = {0.f, 0.f, 0.f, 0.f};
    f32x4 acc[2][4];
    #pragma unroll
    for (int i = 0; i < 2; ++i)
        #pragma unroll
        for (int j = 0; j < 4; ++j) acc[i][j] = z4;

    auto STAGE2 = [&](int k0) {
        #pragma unroll
        for (int hh = 0; hh < 2; ++hh) {
            #pragma unroll
            for (int it = 0; it < 2; ++it)
                GLD16(Ag + (size_t)(it*8)*K + k0 + hh*64, &smem[hh][(w*2 + it)*512]);
            #pragma unroll
            for (int it = 0; it < 4; ++it)
                GLD16(Wg + (size_t)(it*8)*K + k0 + hh*64, &smem[hh][4096 + (w*4 + it)*512]);
        }
    };

    STAGE2(0);
    for (int k0 = 0; k0 < K; k0 += 128) {
        __syncthreads();                       // B1: both sub-tiles landed
        bf16x8 afr[2][4], bfr[2][8];
        #pragma unroll
        for (int hh = 0; hh < 2; ++hh)
            #pragma unroll
            for (int kk = 0; kk < 2; ++kk) {
                #pragma unroll
                for (int i = 0; i < 2; ++i)
                    afr[hh][kk*2+i] = *(const bf16x8*)&smem[hh][(wr + i*16 + lr)*64 + ((kk*32 + lk) ^ swz)];
                #pragma unroll
                for (int j = 0; j < 4; ++j)
                    bfr[hh][kk*4+j] = *(const bf16x8*)&smem[hh][4096 + (wc + j*16 + lr)*64 + ((kk*32 + lk) ^ swz)];
            }
        __syncthreads();                       // B2: reads done, LDS free
        if (k0 + 128 < K) STAGE2(k0 + 128);
        #pragma unroll
        for (int hh = 0; hh < 2; ++hh)
            #pragma unroll
            for (int kk = 0; kk < 2; ++kk)
                #pragma unroll
                for (int i = 0; i < 2; ++i)
                    #pragma unroll
                    for (int j = 0; j < 4; ++j)
                        acc[i][j] = MFMA16(afr[hh][kk*2+i], bfr[hh][kk*4+j], acc[i][j]);
    }
    // last B2 drained all LDS reads -> safe to reuse smem as tr below

    float zf = 0.f;
    if (seg == 1) {
        float f = fptr[0];
        float sp = (f > 20.f) ? f : log1pf(expf(f));
        zf = fminf(fmaxf(sp, 1e-5f), 0.1f);
    }
    bf16_t* tr = &smem[0][0];                  // 128*66 = 8448 <= 12288

    #pragma unroll
    for (int i = 0; i < 2; ++i) {
        float ov[4][4];
        #pragma unroll
        for (int j = 0; j < 4; ++j) {
            const int col = n0 + wc + j*16 + lr;          // 0..1023 within seg
            const float bv = (seg == 0) ? qb[col] : (seg == 2) ? vbias[col] : 0.f;
            const int d  = col & 63;
            const int pi = d >> 1;
            #pragma unroll
            for (int r2 = 0; r2 < 4; ++r2) {
                const int row = m0 + wr + i*16 + g4*4 + r2;
                const int s  = row & (SEQ - 1);
                float val = acc[i][j][r2] + bv;
                if (seg < 2) {
                    // rope pair (even,odd) lives in lanes lr, lr^1
                    float partner = __shfl_xor(val, 1, 64);
                    float c  = ctab[s*32 + pi];
                    float sn = stab[s*32 + pi];
                    val = ((d & 1) == 0) ? (val*c - partner*sn)
                                         : (partner*sn + val*c);
                }
                ov[j][r2] = val;
            }
        }
        if (seg == 1) {
            // scaled_zero: d==0 value of each row held by lane (l&48), j=0
            #pragma unroll
            for (int r2 = 0; r2 < 4; ++r2) {
                float z0 = __shfl(ov[0][r2], (l & 48), 64);
                float zr = (z0 == 0.0f) ? zf : 1.0f;
                #pragma unroll
                for (int j = 0; j < 4; ++j) ov[j][r2] *= zr;
            }
        }
        #pragma unroll
        for (int j = 0; j < 4; ++j) {
            const int col = n0 + wc + j*16 + lr;
            #pragma unroll
            for (int r2 = 0; r2 < 4; ++r2) {
                const int row = m0 + wr + i*16 + g4*4 + r2;
                if (seg == 0)      qbf[(size_t)row*DD + col] = (bf16_t)ov[j][r2];
                else if (seg == 1) kbf[(size_t)row*DD + col] = (bf16_t)ov[j][r2];
                else tr[(col - n0)*66 + (row - m0)] = (bf16_t)ov[j][r2];
            }
        }
    }

    if (seg == 2) {
        __syncthreads();          // tr complete
        const int bb2 = m0 >> 10, s0 = m0 & (SEQ - 1);
        const int d2 = tid >> 1, sh = (tid & 1) * 32;
        const int hh2 = (n0 >> 6) + (d2 >> 6);
        const int dd2 = d2 & 63;
        bf16_t* dst = vt + ((size_t)(bb2*HEADS + hh2)*HDIM + dd2)*S + s0 + sh;
        const bf16_t* srcp = tr + d2*66 + sh;
        #pragma unroll
        for (int k2 = 0; k2 < 4; ++k2)
            *(bf16x8*)(dst + k2*8) = *(const bf16x8*)(srcp + k2*8);
    }
}

// ---------------------------------------------------------------------------
// Fused flash attention, two 128-key K/V tiles per barrier pair (round-17).
// ---------------------------------------------------------------------------
__global__ __launch_bounds__(256) void attn_fused(
    const bf16_t* __restrict__ qbf, const bf16_t* __restrict__ kbf,
    const bf16_t* __restrict__ Vt, bf16_t* __restrict__ O, int S)
{
    __shared__ __align__(16) bf16_t Ks[2][128*64];   // [k][64], swizzled
    __shared__ __align__(16) bf16_t Vs[2][64*128];   // [d][128], swizzled
    __shared__ __align__(16) bf16_t Ps[64*128];      // [q][128], XOR-swizzled

    const int tid = threadIdx.x;
    const int qt = (gridDim.x - 1) - blockIdx.x;  // heavy tiles dispatch first
    const int q0 = qt * 64;
    const int bh = blockIdx.y, b = bh >> 4, hh = bh & 15;
    const int l = tid & 63, w = tid >> 6;
    const int lr = l & 15, g = l >> 4;
    const int lk = g * 8;
    const int swz = (lr & 7) << 3;
    const int ktm = q0 >> 7;                 // last causal 128-key tile
    const int cnt = S - 128*(ktm + 1);       // fully-masked tail key count
    const int myq = q0 + w*16 + lr;          // q this lane holds stats for
    const int qloc = w*16 + lr;              // row in Ps

    bf16x8 qfr[2];
    {
        const bf16_t* qp = qbf + (size_t)(b*S + myq)*DD + hh*HDIM;
        qfr[0] = *(const bf16x8*)(qp + lk);
        qfr[1] = *(const bf16x8*)(qp + 32 + lk);
    }

    float m_run = (cnt > 0) ? 0.f : -3.0e38f;   // masked zeros participate
    float psum = 0.f;
    f32x4 z4 = {0.f, 0.f, 0.f, 0.f};
    f32x4 acc[4];                  // O[q = w*16 + g*4+r][d = j*16+lr]
    #pragma unroll
    for (int j = 0; j < 4; ++j) acc[j] = z4;

    const int sr = l >> 3;
    const int scK = 8 * ((l & 7) ^ (l >> 3));   // K-slot src col (8 rows x 64)
    // V-slot src col (4 rows x 128): row&7 = 4*(it&1)+g
    const int scV0 = (lr * 8) ^ ((4*0 + g) << 3);
    const int scV1 = (lr * 8) ^ ((4*1 + g) << 3);

    auto STAGEKV = [&](int buf, int kt) {
        const bf16_t* Kg = kbf + (size_t)(b*S + kt*128)*DD + hh*HDIM;
        #pragma unroll
        for (int it = 0; it < 4; ++it) {
            const int krow = (w*4 + it)*8 + sr;
            GLD16(Kg + (size_t)krow*DD + scK, &Ks[buf][(w*4 + it)*512]);
        }
        const bf16_t* Vg = Vt + ((size_t)bh*HDIM)*S + kt*128;
        #pragma unroll
        for (int it = 0; it < 4; ++it) {
            const int drow = (w*4 + it)*4 + g;
            GLD16(Vg + (size_t)drow*S + ((it & 1) ? scV1 : scV0),
                  &Vs[buf][(w*4 + it)*512]);
        }
    };

    for (int kt0 = 0; kt0 <= ktm; kt0 += 2) {
        __syncthreads();                       // prev pair's reads done
        STAGEKV(0, kt0);
        if (kt0 + 1 <= ktm) STAGEKV(1, kt0 + 1);
        __syncthreads();                       // pair staged (vmcnt drained)

        #pragma unroll
        for (int half = 0; half < 2; ++half) {
            const int kt = kt0 + half;
            if (kt > ktm) continue;

            float sv[8][4];
            float mtile = -3.0e38f;
            #pragma unroll
            for (int f = 0; f < 8; ++f) {
                bf16x8 ka0 = *(const bf16x8*)&Ks[half][(f*16 + lr)*64 + (lk ^ swz)];
                bf16x8 ka1 = *(const bf16x8*)&Ks[half][(f*16 + lr)*64 + ((32 + lk) ^ swz)];
                f32x4 t = z4;
                t = MFMA16(ka0, qfr[0], t);
                t = MFMA16(ka1, qfr[1], t);
                #pragma unroll
                for (int r = 0; r < 4; ++r) {
                    const int key = kt*128 + f*16 + g*4 + r;
                    float v = t[r] * 0.125f;       // HD^-0.5; zm folded into kbf
                    v = (key <= myq) ? v : 0.f;
                    sv[f][r] = v;
                    mtile = fmaxf(mtile, v);
                }
            }
            mtile = fmaxf(mtile, __shfl_xor(mtile, 16, 64));
            mtile = fmaxf(mtile, __shfl_xor(mtile, 32, 64));
            const float m_new = fmaxf(m_run, mtile);
            const float fac = expf(m_run - m_new);
            m_run = m_new;

            float ps_t = 0.f;
            #pragma unroll
            for (int f = 0; f < 8; ++f) {
                bf16x4 pk;
                #pragma unroll
                for (int r = 0; r < 4; ++r) {
                    float p = expf(sv[f][r] - m_new);
                    ps_t += p;
                    pk[r] = (bf16_t)p;
                }
                const int byteoff = (qloc*256 + f*32 + g*8) ^ ((lr & 7) << 4);
                *(bf16x4*)((char*)Ps + byteoff) = pk;
            }
            ps_t += __shfl_xor(ps_t, 16, 64);
            ps_t += __shfl_xor(ps_t, 32, 64);
            psum = psum * fac + ps_t;

            #pragma unroll
            for (int r = 0; r < 4; ++r) {
                const float fr_ = __shfl(fac, g*4 + r, 64);
                #pragma unroll
                for (int j = 0; j < 4; ++j) acc[j][r] *= fr_;
            }

            #pragma unroll
            for (int kk = 0; kk < 4; ++kk) {
                const int rboff = (qloc*256 + kk*64 + g*16) ^ ((lr & 7) << 4);
                bf16x8 pa = *(const bf16x8*)((char*)Ps + rboff);
                #pragma unroll
                for (int j = 0; j < 4; ++j) {
                    bf16x8 vb = *(const bf16x8*)&Vs[half][(j*16 + lr)*128 + ((kk*32 + lk) ^ swz)];
                    acc[j] = MFMA16(pa, vb, acc[j]);
                }
            }
        }
    }

    // causal tail: sum_{k in tail} Vt[bh][d][k] per wave (lane l -> d=l)
    float vtail = 0.f;
    if (cnt > 0) {
        psum += (float)cnt * expf(-m_run);
        const bf16_t* vp = Vt + ((size_t)bh*HDIM + l)*S + 128*(ktm + 1);
        for (int k = 0; k < cnt; k += 8) {
            bf16x8 v = *(const bf16x8*)(vp + k);
            #pragma unroll
            for (int e = 0; e < 8; ++e) vtail += (float)v[e];
        }
    }

    #pragma unroll
    for (int r = 0; r < 4; ++r) {
        const float m_r  = __shfl(m_run, g*4 + r, 64);
        const float ps_r = __shfl(psum,  g*4 + r, 64);
        const float inv = 1.0f / ps_r;
        const float tailf = (cnt > 0) ? expf(-m_r) : 0.f;
        const int qrow = q0 + w*16 + g*4 + r;
        const size_t rowbase = (size_t)(b*S + qrow)*DD + hh*HDIM;
        #pragma unroll
        for (int j = 0; j < 4; ++j) {
            const float vt_j = __shfl(vtail, j*16 + lr, 64);
            float val = acc[j][r];
            if (cnt > 0) val += tailf * vt_j;
            O[rowbase + j*16 + lr] = (bf16_t)(val * inv);
        }
    }
}

// ---------------------------------------------------------------------------
extern "C" void kernel_launch(void* const* d_in, const int* in_sizes, int n_in,
                              void* d_out, int out_size, void* d_ws, size_t ws_size,
                              hipStream_t stream)
{
    const int S = SEQ;
    const int B = in_sizes[0] / S;     // 2
    const int M = B * S;               // 2048
    const int BH = B * HEADS;          // 32

    const int*   x       = (const int*)  d_in[0];
    const float* tok_emb = (const float*)d_in[2];
    const float* pos_emb = (const float*)d_in[3];
    const float* rif     = (const float*)d_in[4];
    const float* rbias   = (const float*)d_in[5];
    const float* brif    = (const float*)d_in[6];
    const float* bbias   = (const float*)d_in[7];
    const float* lna     = (const float*)d_in[8];
    const float* qw      = (const float*)d_in[9];
    const float* qb      = (const float*)d_in[10];
    const float* kw      = (const float*)d_in[11];
    const float* vw      = (const float*)d_in[12];
    const float* vbias   = (const float*)d_in[13];
    const float* ow      = (const float*)d_in[14];
    const float* ob      = (const float*)d_in[15];
    const float* factor  = (const float*)d_in[16];
    const float* lnc     = (const float*)d_in[17];
    const float* w1      = (const float*)d_in[18];
    const float* b1      = (const float*)d_in[19];
    const float* w2      = (const float*)d_in[20];
    const float* b2      = (const float*)d_in[21];
    const float* lnd     = (const float*)d_in[22];

    char* ob_ = (char*)d_out;
    const size_t MiB = 1024*1024;
    bf16_t* h      = (bf16_t*)(ob_ + 0*MiB);     // 4 MiB (bf16 residual)
    bf16_t* h2     = (bf16_t*)(ob_ + 8*MiB);     // 4 MiB (bf16 residual)
    bf16_t* qbf    = (bf16_t*)(ob_ + 16*MiB);    // 4 MiB
    bf16_t* kbf    = (bf16_t*)(ob_ + 20*MiB);    // 4 MiB
    bf16_t* vt     = (bf16_t*)(ob_ + 24*MiB);    // 4 MiB  Vt[b][h][d][S]
    bf16_t* attno  = (bf16_t*)(ob_ + 28*MiB);    // 4 MiB
    bf16_t* m1     = (bf16_t*)(ob_ + 32*MiB);    // 16 MiB
    float*  ctab   = (float*)(ob_ + 50*MiB);     // 128 KiB
    float*  stab   = (float*)(ob_ + 51*MiB);     // 128 KiB
    bf16_t* qw_bf  = (bf16_t*)(ob_ + 64*MiB);    // 8 MiB (4 layers)
    bf16_t* kw_bf  = (bf16_t*)(ob_ + 72*MiB);
    bf16_t* vw_bf  = (bf16_t*)(ob_ + 80*MiB);
    bf16_t* ow_bf  = (bf16_t*)(ob_ + 88*MiB);
    bf16_t* w1_bf  = (bf16_t*)(ob_ + 96*MiB);    // 32 MiB
    bf16_t* w2_bf  = (bf16_t*)(ob_ + 128*MiB);   // 32 MiB -> ends 160 < 250 MiB

    bf16_t* hn      = (bf16_t*)d_ws;             // 4 MiB
    bf16_t* temb_bf = (bf16_t*)((char*)d_ws + 4*MiB);
    const bool big_ws = ws_size >= (size_t)(70*MiB);

    // --- single batched weight conversion (all counts % 4096 == 0) ---
    {
        CvtBatch cb;
        const float* srcs[7] = {qw, kw, vw, ow, w1, w2, tok_emb};
        bf16_t*      dsts[7] = {qw_bf, kw_bf, vw_bf, ow_bf, w1_bf, w2_bf, temb_bf};
        const long   ns[7]   = {(long)NLAYER*DD*DD, (long)NLAYER*DD*DD,
                                (long)NLAYER*DD*DD, (long)NLAYER*DD*DD,
                                (long)NLAYER*FFDIM*DD, (long)NLAYER*FFDIM*DD,
                                (long)NVOCAB*DD};
        int nseg = big_ws ? 7 : 6;
        int acc = 0;
        for (int s = 0; s < 7; ++s) {
            cb.src[s] = srcs[s]; cb.dst[s] = dsts[s];
            cb.blk0[s] = acc;
            if (s < nseg) acc += (int)(ns[s] / 4096);
        }
        cb.nseg = nseg;
        cvt_batch<<<acc, 256, 0, stream>>>(cb);
    }
    ropetab_kernel<<<(S*32)/256, 256, 0, stream>>>(brif, bbias, ctab, stab);

    dim3 gMLP1(FFDIM/128, M/64);        // 32 x 32 = 1024 blocks (4/CU)
    dim3 gS64(DD/64,    M/64);          // 64x64-tile GEMMs: 512 blocks (2/CU)
    dim3 gV256(NVOCAB/256, M/256);      // 125 x 8 = 1000 blocks
    dim3 gVfb(NVOCAB/128, M/128);
    dim3 gQKV(3*8, M/64);               // 24 x 32 = 768 blocks (3/CU)
    dim3 gATT(S/64, BH);

    embed_rope_kernel<<<M, 512, 0, stream>>>(x, tok_emb, pos_emb, rif, rbias, h, S);

    for (int l = 0; l < NLAYER; ++l) {
        const size_t wo = (size_t)l * DD * DD;
        const size_t fo = (size_t)l * FFDIM * DD;
        rmsnorm_kernel<<<M, 256, 0, stream>>>(h, lna + l*DD, hn);
        qkv_gemm<<<gQKV, 256, 0, stream>>>(hn, qw_bf + wo, kw_bf + wo, vw_bf + wo,
                                           qb + l*DD, vbias + l*DD, ctab, stab,
                                           factor + l, qbf, kbf, vt, S);
        attn_fused<<<gATT, 256, 0, stream>>>(qbf, kbf, vt, attno, S);
        // h2 = attno @ ow^T + ob + h
        gemm_bf_s64<<<gS64, 256, 0, stream>>>(attno, ow_bf + wo, ob + l*DD, h, nullptr,
                                              h2, M, DD, DD);
        rmsnorm_kernel<<<M, 256, 0, stream>>>(h2, lnc + l*DD, hn);
        // m1 = relu(hn @ w1^T + b1), bf16 out
        gemm_bf_s<<<gMLP1, 256, 0, stream>>>(hn, w1_bf + fo, b1 + l*FFDIM,
                                             nullptr, m1, M, FFDIM, DD, 1, 1);
        // h_new = m1 @ w2^T + b2 + h2 + h   (== 2*h_old + attn + mlp)
        gemm_bf_s64<<<gS64, 256, 0, stream>>>(m1, w2_bf + fo, b2 + l*DD, h2, h,
                                              h, M, DD, FFDIM);
    }

    rmsnorm_kernel<<<M, 256, 0, stream>>>(h, lnd, hn);
    if (big_ws) {
        hipFuncSetAttribute((const void*)gemm256_bf,
                            hipFuncAttributeMaxDynamicSharedMemorySize, 131072);
        gemm256_bf<<<gV256, 512, 131072, stream>>>(hn, temb_bf, (float*)d_out,
                                                   M, NVOCAB);
    } else {
        gemm_bfw32<<<gVfb, 256, 0, stream>>>(hn, tok_emb, (float*)d_out, M, NVOCAB, DD);
    }
}